// Round 8
// baseline (911.990 us; speedup 1.0000x reference)
//
#include <hip/hip_runtime.h>

#define NB 16
#define TT 750
#define DD 2048
#define KK 8
#define CC 21
#define NT 12000

// EM: 12 chunks of 64 rows (matches fused score tiling; 12*64=768 >= 750)
#define EM_CH 12
// pred pass2: 4 t-chunks of 188 rows (4*188 = 752 >= 750)
#define PF_CH 4
#define PF_TCH 188

typedef __bf16 bf16;
typedef __attribute__((ext_vector_type(4))) float floatx4;
typedef __attribute__((ext_vector_type(8))) __bf16 bf16x8;
typedef __attribute__((ext_vector_type(4))) __bf16 bf16x4;

__device__ __forceinline__ float wave_allreduce_sum(float v) {
#pragma unroll
  for (int m = 32; m > 0; m >>= 1) v += __shfl_xor(v, m, 64);
  return v;
}

__device__ __forceinline__ void async_lds16(const bf16* g, bf16* l) {
  __builtin_amdgcn_global_load_lds(
      (const __attribute__((address_space(1))) void*)(g),
      (__attribute__((address_space(3))) void*)(l), 16, 0, 0);
}

// ============ fused prep: W transpose+bf16 | ac_norm | mu_norm0 | x->bf16 =======
__global__ __launch_bounds__(256) void k_prep(
    const float* __restrict__ W, bf16* __restrict__ Wt,
    const float* __restrict__ ac, const float* __restrict__ fg,
    float* __restrict__ nacf, bf16* __restrict__ nacb,
    const float* __restrict__ mup, float* __restrict__ nmu, bf16* __restrict__ nmub,
    const float* __restrict__ x, bf16* __restrict__ Ab) {
  int b = blockIdx.x, tid = threadIdx.x;
  __shared__ float tile[32][33];
  __shared__ float sb[4];
  if (b < 4096) {
    int j0 = (b & 63) * 32, k0 = (b >> 6) * 32;
    int tx = tid & 31, ty = tid >> 5;
#pragma unroll
    for (int i = 0; i < 4; i++)
      tile[ty + 8 * i][tx] = W[(size_t)(k0 + ty + 8 * i) * DD + j0 + tx];
    __syncthreads();
#pragma unroll
    for (int i = 0; i < 4; i++)
      Wt[(size_t)(j0 + ty + 8 * i) * DD + k0 + tx] = (bf16)tile[tx][ty + 8 * i];
    return;
  }
  if (b < 4128) {
    int r = b - 4096;
    int d0 = tid * 8;
    if (r >= 22) {
#pragma unroll
      for (int j = 0; j < 8; j++) nacb[(size_t)r * DD + d0 + j] = (bf16)0.f;
      return;
    }
    const float* src = (r < 21) ? (ac + (size_t)r * DD) : fg;
    float v[8];
    floatx4 a = *(const floatx4*)(src + d0);
    floatx4 c = *(const floatx4*)(src + d0 + 4);
    v[0]=a.x; v[1]=a.y; v[2]=a.z; v[3]=a.w; v[4]=c.x; v[5]=c.y; v[6]=c.z; v[7]=c.w;
    float ss = 0.f;
#pragma unroll
    for (int j = 0; j < 8; j++) ss += v[j] * v[j];
    ss = wave_allreduce_sum(ss);
    int lane = tid & 63, wid = tid >> 6;
    if (lane == 0) sb[wid] = ss;
    __syncthreads();
    float inv = 1.f / (sqrtf(sb[0] + sb[1] + sb[2] + sb[3]) + 1e-9f);
#pragma unroll
    for (int j = 0; j < 8; j++) {
      float nv = v[j] * inv;
      nacf[(size_t)r * DD + d0 + j] = nv;
      nacb[(size_t)r * DD + d0 + j] = (bf16)nv;
    }
    return;
  }
  if (b < 4256) {
    int bb = b - 4128;  // n*8+k
    int n = bb >> 3, k = bb & 7;
    int lane = tid & 63, wid = tid >> 6;
    const float* p = mup + (size_t)k * DD + tid * 8;
    float v[8];
    floatx4 a = *(const floatx4*)p;
    floatx4 c = *(const floatx4*)(p + 4);
    v[0]=a.x; v[1]=a.y; v[2]=a.z; v[3]=a.w; v[4]=c.x; v[5]=c.y; v[6]=c.z; v[7]=c.w;
    float ss = 0.f;
#pragma unroll
    for (int j = 0; j < 8; j++) ss += v[j] * v[j];
    ss = wave_allreduce_sum(ss);
    if (lane == 0) sb[wid] = ss;
    __syncthreads();
    float inv = 1.f / (sqrtf(sb[0] + sb[1] + sb[2] + sb[3]) + 1e-9f);
    float* q = nmu + (size_t)bb * DD + tid * 8;
    bf16* qb = nmub + (size_t)(n * 16 + k) * DD + tid * 8;
#pragma unroll
    for (int j = 0; j < 8; j++) {
      float nv = v[j] * inv;
      q[j] = nv;
      qb[j] = (bf16)nv;
    }
    return;
  }
  int unit0 = (b - 4256) * 4;
#pragma unroll
  for (int u = 0; u < 4; u++) {
    size_t base = ((size_t)(unit0 + u) * 256 + tid) * 8;
    int row = (int)(base >> 11);
    bf16x8 o = {};
    if (row < NT) {
      floatx4 a = *(const floatx4*)(x + base);
      floatx4 c = *(const floatx4*)(x + base + 4);
      o[0]=(bf16)a.x; o[1]=(bf16)a.y; o[2]=(bf16)a.z; o[3]=(bf16)a.w;
      o[4]=(bf16)c.x; o[5]=(bf16)c.y; o[6]=(bf16)c.z; o[7]=(bf16)c.w;
    }
    *(bf16x8*)(Ab + base) = o;
  }
}

// ============ embedding GEMM (round-5 structure + XCD m-band swizzle) ===========
__global__ __launch_bounds__(256) void k_gemm(
    const bf16* __restrict__ Ab, const bf16* __restrict__ Bt,
    const float* __restrict__ bias,
    float* __restrict__ Cout, bf16* __restrict__ Cb, float* __restrict__ rowsq) {
  __shared__ bf16 As[128 * 64];
  __shared__ bf16 Bs[128 * 64];
  int tid = threadIdx.x;
  int bid = blockIdx.x;
  int wid2 = (bid & 7) * 188 + (bid >> 3);  // XCD x owns wid2 in [188x, 188(x+1))
  int mt = wid2 >> 4, nt = wid2 & 15;
  int m0 = mt * 128, n0 = nt * 128;
  int wid = tid >> 6, lane = tid & 63;
  int wm = (wid >> 1) * 64, wn = (wid & 1) * 64;
  int lrow = lane & 15, lko = (lane >> 4) * 8;
  int lr7 = lrow & 7;
  floatx4 acc[4][4] = {};
  int crow = tid >> 3;
  int jg = ((tid & 7) ^ (crow & 7)) * 8;
  const bf16* gA = Ab + (size_t)(m0 + crow) * DD + jg;
  const bf16* gB = Bt + (size_t)(n0 + crow) * DD + jg;
  bf16* lA = As + tid * 8;
  bf16* lB = Bs + tid * 8;
  for (int k0 = 0; k0 < DD; k0 += 64) {
#pragma unroll
    for (int s = 0; s < 4; s++)
      async_lds16(gA + (size_t)(32 * s) * DD + k0, lA + 2048 * s);
#pragma unroll
    for (int s = 0; s < 4; s++)
      async_lds16(gB + (size_t)(32 * s) * DD + k0, lB + 2048 * s);
    __syncthreads();
#pragma unroll
    for (int ks = 0; ks < 64; ks += 32) {
      bf16x8 af[4], bfr[4];
#pragma unroll
      for (int i = 0; i < 4; i++) {
        int sw = (((ks + lko) >> 3) ^ lr7) * 8;
        af[i] = *(const bf16x8*)(As + (wm + i * 16 + lrow) * 64 + sw);
      }
#pragma unroll
      for (int jj = 0; jj < 4; jj++) {
        int sw = (((ks + lko) >> 3) ^ lr7) * 8;
        bfr[jj] = *(const bf16x8*)(Bs + (wn + jj * 16 + lrow) * 64 + sw);
      }
#pragma unroll
      for (int i = 0; i < 4; i++)
#pragma unroll
        for (int jj = 0; jj < 4; jj++)
          acc[i][jj] = __builtin_amdgcn_mfma_f32_16x16x32_bf16(af[i], bfr[jj], acc[i][jj], 0, 0, 0);
    }
    __syncthreads();
  }
  int quad = lane >> 4;
  float bv[4];
#pragma unroll
  for (int jj = 0; jj < 4; jj++) bv[jj] = bias[n0 + wn + jj * 16 + lrow];
#pragma unroll
  for (int i = 0; i < 4; i++) {
#pragma unroll
    for (int r = 0; r < 4; r++) {
      int row = m0 + wm + i * 16 + quad * 4 + r;
      bool ok = (row < NT);
      float sq = 0.f;
#pragma unroll
      for (int jj = 0; jj < 4; jj++) {
        int col = n0 + wn + jj * 16 + lrow;
        float v = acc[i][jj][r] + bv[jj];
        v = fmaxf(v, 0.f);
        if (ok) {
          Cout[(size_t)row * DD + col] = v;
          Cb[(size_t)row * DD + col] = (bf16)v;
        }
        sq += v * v;
      }
#pragma unroll
      for (int m = 1; m < 16; m <<= 1) sq += __shfl_xor(sq, m, 64);
      if (ok && lrow == 0) atomicAdd(&rowsq[row], sq);
    }
  }
}

// ============ fused EM iteration: BK=256 score + in-LDS z + block-local accum ====
// Phase A = round-5 verified k_score body (BK=256 deep pipeline). z kept in LDS.
// Phase B re-reads the SAME 64 rows this block just streamed (256 KB, L2-hot) and
// accumulates the per-chunk mu partials. Fan-in via part2 -> k_mu_finish (separate
// launch; all cross-block ordering stays at kernel boundaries).
__global__ __launch_bounds__(256) void k_em_iter(
    const bf16* __restrict__ Xb, const bf16* __restrict__ nmub,
    const float* __restrict__ rowsq,
    float* __restrict__ z, float* __restrict__ rowsum, float* __restrict__ part2) {
  __shared__ bf16 As[2][64 * 256];
  __shared__ bf16 Bs[2][16 * 256];
  __shared__ float zs[64 * 8];
  int tid = threadIdx.x, lane = tid & 63, w = tid >> 6;
  int m0 = blockIdx.x * 64, n = blockIdx.y;
  int lrow = lane & 15, lko = (lane >> 4) * 8, lr7 = lrow & 7;
  int scg = tid & 31;
  int srow = tid >> 5;
  const bf16* gXn = Xb + (size_t)(n * TT + m0) * DD;
  const bf16* gBn = nmub + (size_t)(n * 16) * DD;
#pragma unroll
  for (int r = 0; r < 8; r++) {
    int row = r * 8 + srow;
    int cgg = (scg & 24) | ((scg & 7) ^ (row & 7));
    async_lds16(gXn + (size_t)row * DD + cgg * 8, &As[0][r * 2048 + tid * 8]);
  }
#pragma unroll
  for (int r = 0; r < 2; r++) {
    int row = r * 8 + srow;
    int cgg = (scg & 24) | ((scg & 7) ^ (row & 7));
    async_lds16(gBn + (size_t)row * DD + cgg * 8, &Bs[0][r * 2048 + tid * 8]);
  }
  floatx4 acc = {};
  int buf = 0;
  for (int k0 = 0; k0 < DD; k0 += 256) {
    __syncthreads();
    if (k0 + 256 < DD) {
#pragma unroll
      for (int r = 0; r < 8; r++) {
        int row = r * 8 + srow;
        int cgg = (scg & 24) | ((scg & 7) ^ (row & 7));
        async_lds16(gXn + (size_t)row * DD + k0 + 256 + cgg * 8,
                    &As[buf ^ 1][r * 2048 + tid * 8]);
      }
#pragma unroll
      for (int r = 0; r < 2; r++) {
        int row = r * 8 + srow;
        int cgg = (scg & 24) | ((scg & 7) ^ (row & 7));
        async_lds16(gBn + (size_t)row * DD + k0 + 256 + cgg * 8,
                    &Bs[buf ^ 1][r * 2048 + tid * 8]);
      }
    }
    int arow = w * 16 + lrow;
#pragma unroll
    for (int ks = 0; ks < 256; ks += 32) {
      int cg = (ks + lko) >> 3;
      int cgl = (cg & 24) | ((cg & 7) ^ lr7);
      bf16x8 a = *(const bf16x8*)(&As[buf][arow * 256 + cgl * 8]);
      bf16x8 b = *(const bf16x8*)(&Bs[buf][lrow * 256 + cgl * 8]);
      acc = __builtin_amdgcn_mfma_f32_16x16x32_bf16(a, b, acc, 0, 0, 0);
    }
    buf ^= 1;
  }
  int quad = lane >> 4;
  int k = lrow;
  float pacc = 0.f;
#pragma unroll
  for (int r = 0; r < 4; r++) {
    int tl = w * 16 + quad * 4 + r;  // local row 0..63
    int trow = m0 + tl;
    bool valid = (trow < TT);
    float rq = valid ? rowsq[n * TT + trow] : 1.f;
    float s = acc[r] * (5.f / (sqrtf(rq) + 1e-9f));
    float mx = s;
    mx = fmaxf(mx, __shfl_xor(mx, 1, 64));
    mx = fmaxf(mx, __shfl_xor(mx, 2, 64));
    mx = fmaxf(mx, __shfl_xor(mx, 4, 64));
    float e = __expf(s - mx);
    float se = e;
    se += __shfl_xor(se, 1, 64);
    se += __shfl_xor(se, 2, 64);
    se += __shfl_xor(se, 4, 64);
    float zz = e / se;
    zz = (valid && k < 8) ? zz : 0.f;
    if (k < 8) {
      if (valid) z[(size_t)(n * TT + trow) * 8 + k] = zz;
      zs[tl * 8 + k] = zz;  // zero for invalid rows -> phase B contribution is 0
    }
    pacc += zz;
  }
  pacc += __shfl_xor(pacc, 16, 64);
  pacc += __shfl_xor(pacc, 32, 64);
  if (lane < 8) atomicAdd(&rowsum[n * 8 + lane], pacc);
  __syncthreads();
  // ---- phase B: mu partials for this 64-row chunk (block-local re-read, L2-hot)
  float acc2[8][8] = {};
  const bf16* xp = Xb + (size_t)(n * TT + m0) * DD + tid * 8;
  bf16x8 x0 = *(const bf16x8*)xp;
  bf16x8 x1 = *(const bf16x8*)(xp + DD);
  for (int tt = 0; tt < 64; tt++) {
    bf16x8 cur = x0;
    x0 = x1;
    if (tt + 2 < 64) x1 = *(const bf16x8*)(xp + (size_t)(tt + 2) * DD);
    float xv[8];
#pragma unroll
    for (int j = 0; j < 8; j++) xv[j] = (float)cur[j];
    floatx4 za = *(const floatx4*)&zs[tt * 8];
    floatx4 zb4 = *(const floatx4*)&zs[tt * 8 + 4];
    float zk[8] = {za.x, za.y, za.z, za.w, zb4.x, zb4.y, zb4.z, zb4.w};
#pragma unroll
    for (int kk = 0; kk < 8; kk++)
#pragma unroll
      for (int j = 0; j < 8; j++) acc2[kk][j] += zk[kk] * xv[j];
  }
  float* pb = part2 + ((size_t)(blockIdx.x * 16 + n) * 8) * DD + tid * 8;
#pragma unroll
  for (int kk = 0; kk < 8; kk++) {
    floatx4 lo = {acc2[kk][0], acc2[kk][1], acc2[kk][2], acc2[kk][3]};
    floatx4 hi = {acc2[kk][4], acc2[kk][5], acc2[kk][6], acc2[kk][7]};
    *(floatx4*)(pb + (size_t)kk * DD) = lo;
    *(floatx4*)(pb + (size_t)kk * DD + 4) = hi;
  }
}

// ============ EM finish =========================================================
__global__ void k_mu_finish(const float* __restrict__ part2, const float* __restrict__ rs,
                            float* __restrict__ accS_raw, float* __restrict__ mu_ws,
                            float* __restrict__ mu_out, float* __restrict__ nmu_out,
                            bf16* __restrict__ nmub) {
  int b = blockIdx.x;  // n*8+k
  int n = b >> 3, k = b & 7;
  int tid = threadIdx.x, lane = tid & 63, wid = tid >> 6;
  int d0 = tid * 8;
  float s[8] = {};
#pragma unroll 4
  for (int c = 0; c < EM_CH; c++) {
    const float* p = part2 + ((size_t)(c * 16 + n) * 8 + k) * DD + d0;
    floatx4 a = *(const floatx4*)p;
    floatx4 cc = *(const floatx4*)(p + 4);
    s[0] += a.x; s[1] += a.y; s[2] += a.z; s[3] += a.w;
    s[4] += cc.x; s[5] += cc.y; s[6] += cc.z; s[7] += cc.w;
  }
  if (accS_raw != nullptr) {
#pragma unroll
    for (int j = 0; j < 8; j++) accS_raw[(size_t)b * DD + d0 + j] = s[j];
    return;
  }
  float invr = 1.f / (rs[b] + 1e-9f);
  float m[8];
#pragma unroll
  for (int j = 0; j < 8; j++) m[j] = s[j] * invr;
#pragma unroll
  for (int j = 0; j < 8; j++) mu_ws[(size_t)b * DD + d0 + j] = m[j];
  if (mu_out != nullptr) {
#pragma unroll
    for (int j = 0; j < 8; j++) mu_out[(size_t)b * DD + d0 + j] = m[j];
  }
  float ss = 0.f;
#pragma unroll
  for (int j = 0; j < 8; j++) ss += m[j] * m[j];
  ss = wave_allreduce_sum(ss);
  __shared__ float sb[4];
  if (lane == 0) sb[wid] = ss;
  __syncthreads();
  float inv = 1.f / (sqrtf(sb[0] + sb[1] + sb[2] + sb[3]) + 1e-9f);
  bf16* qb = nmub + (size_t)(n * 16 + k) * DD + d0;
#pragma unroll
  for (int j = 0; j < 8; j++) {
    float nv = m[j] * inv;
    nmu_out[(size_t)b * DD + d0 + j] = nv;
    qb[j] = (bf16)nv;
  }
}

// ============ Woodbury + mu_pred ================================================
__global__ void k_wood_mupred(const float* __restrict__ z, const float* __restrict__ rowsum,
                              const float* __restrict__ S, const float* __restrict__ mu,
                              float* __restrict__ G,
                              const float* __restrict__ nmu, const float* __restrict__ nacf,
                              float* __restrict__ mupred) {
  int tid = threadIdx.x;
  if (blockIdx.x >= 16) {
    int b = blockIdx.x - 16;
    int lane = tid & 63, wid = tid >> 6;
    const float* v = nmu + (size_t)b * DD;
    __shared__ float scr[21];
    for (int c = wid; c < 21; c += 4) {
      const float* a = nacf + (size_t)c * DD;
      float s = 0.f;
      for (int i = lane * 4; i < DD; i += 256) {
        floatx4 vv = *(const floatx4*)(v + i);
        floatx4 aa = *(const floatx4*)(a + i);
        s += vv.x * aa.x + vv.y * aa.y + vv.z * aa.z + vv.w * aa.w;
      }
      s = wave_allreduce_sum(s);
      if (lane == 0) scr[c] = s * 20.f;
    }
    __syncthreads();
    if (tid == 0) {
      float mx = scr[0];
      for (int c = 1; c < 21; c++) mx = fmaxf(mx, scr[c]);
      float se = 0.f;
      for (int c = 0; c < 21; c++) se += __expf(scr[c] - mx);
      float inv = 1.f / se;
      for (int c = 0; c < 21; c++) mupred[(size_t)b * 21 + c] = __expf(scr[c] - mx) * inv;
    }
    return;
  }
  int n = blockIdx.x;
  __shared__ float VU[8][8];
  __shared__ float Mi[8][8];
  __shared__ float invrs[8];
  __shared__ float vus[64][4];
  if (tid < 8) invrs[tid] = 1.f / (rowsum[n * 8 + tid] + 1e-9f);
  {
    int pr = tid >> 2, sl = tid & 3;
    int jj = pr >> 3, kk = pr & 7;
    float s = 0.f;
    for (int t = sl; t < TT; t += 4) {
      const float* zp = z + (size_t)(n * TT + t) * 8;
      s += zp[jj] * zp[kk];
    }
    vus[pr][sl] = s;
  }
  __syncthreads();
  if (tid < 64)
    VU[tid >> 3][tid & 7] =
        (vus[tid][0] + vus[tid][1] + vus[tid][2] + vus[tid][3]) * invrs[tid >> 3];
  __syncthreads();
  if (tid == 0) {
    float M[8][16];
    for (int i = 0; i < 8; i++)
      for (int jj = 0; jj < 8; jj++) {
        M[i][jj] = ((i == jj) ? 1.f : 0.f) - 0.25f * VU[i][jj];
        M[i][8 + jj] = (i == jj) ? 1.f : 0.f;
      }
    for (int c = 0; c < 8; c++) {
      float pv = 1.f / M[c][c];
      for (int jj = 0; jj < 16; jj++) M[c][jj] *= pv;
      for (int rr = 0; rr < 8; rr++)
        if (rr != c) {
          float f = M[rr][c];
          for (int jj = 0; jj < 16; jj++) M[rr][jj] -= f * M[c][jj];
        }
    }
    for (int i = 0; i < 8; i++)
      for (int jj = 0; jj < 8; jj++) Mi[i][jj] = M[i][8 + jj];
  }
  __syncthreads();
  const float* mun = mu + (size_t)n * 8 * DD;
  const float* Sn = S + (size_t)n * 8 * DD;
  float* Gn = G + (size_t)n * 8 * DD;
  for (int d = tid; d < DD; d += 256) {
    float m[8], P[8];
#pragma unroll
    for (int k = 0; k < 8; k++) m[k] = mun[k * DD + d];
#pragma unroll
    for (int k = 0; k < 8; k++) {
      float s = 0.f;
#pragma unroll
      for (int jj = 0; jj < 8; jj++) s += VU[k][jj] * m[jj];
      P[k] = 0.5f * s + Sn[k * DD + d] * invrs[k];
    }
#pragma unroll
    for (int jj = 0; jj < 8; jj++) {
      float s = 0.f;
#pragma unroll
      for (int k = 0; k < 8; k++) s += Mi[jj][k] * P[k];
      Gn[jj * DD + d] = 0.5f * (0.5f * m[jj] + 0.25f * s);
    }
  }
}

// ============ RW pass ===========================================================
__global__ __launch_bounds__(256) void k_rw_passC(
    const bf16* __restrict__ Xb, const float* __restrict__ z,
    const float* __restrict__ G, bf16* __restrict__ refb,
    float* __restrict__ invr) {
  int n = blockIdx.x, ch = blockIdx.y, tid = threadIdx.x;
  int lane = tid & 63, wid = tid >> 6;
  int d0 = tid * 8;
  int t0 = ch * 30;
  const float* Gn = G + (size_t)n * 8 * DD;
  float gr[8][8];
#pragma unroll
  for (int k = 0; k < 8; k++) {
    floatx4 a = *(const floatx4*)(Gn + k * DD + d0);
    floatx4 b = *(const floatx4*)(Gn + k * DD + d0 + 4);
    gr[k][0]=a.x; gr[k][1]=a.y; gr[k][2]=a.z; gr[k][3]=a.w;
    gr[k][4]=b.x; gr[k][5]=b.y; gr[k][6]=b.z; gr[k][7]=b.w;
  }
  __shared__ float red[30][4];
  const bf16* xrow = Xb + (size_t)n * TT * DD;
  bf16x8 xg = *(const bf16x8*)(xrow + (size_t)t0 * DD + d0);
  for (int tt = 0; tt < 30; tt++) {
    int t = t0 + tt;
    bf16x8 x8 = xg;
    if (tt + 1 < 30) xg = *(const bf16x8*)(xrow + (size_t)(t + 1) * DD + d0);
    const float* zp = z + (size_t)(n * TT + t) * 8;
    floatx4 za = *(const floatx4*)zp;
    floatx4 zb4 = *(const floatx4*)(zp + 4);
    float zt[8] = {za.x, za.y, za.z, za.w, zb4.x, zb4.y, zb4.z, zb4.w};
    float r[8];
#pragma unroll
    for (int j = 0; j < 8; j++) {
      float s = 0.5f * (float)x8[j];
#pragma unroll
      for (int k = 0; k < 8; k++) s += zt[k] * gr[k][j];
      r[j] = s;
    }
    bf16x8 ro;
#pragma unroll
    for (int j = 0; j < 8; j++) ro[j] = (bf16)r[j];
    *(bf16x8*)(refb + (size_t)(n * TT + t) * DD + d0) = ro;
    float ss = 0.f;
#pragma unroll
    for (int j = 0; j < 8; j++) ss += r[j] * r[j];
    ss = wave_allreduce_sum(ss);
    if (lane == 0) red[tt][wid] = ss;
  }
  __syncthreads();
  if (tid < 30) {
    float tot = red[tid][0] + red[tid][1] + red[tid][2] + red[tid][3];
    invr[n * TT + t0 + tid] = 1.f / (sqrtf(tot) + 1e-9f);
  }
}

// ============ pred pass1 (BK=256 deep-pipelined staging) ========================
__global__ __launch_bounds__(256) void k_pred_p1(
    const bf16* __restrict__ Xb, const bf16* __restrict__ nacb,
    const float* __restrict__ invn, int mode,
    float* __restrict__ out_frm, float* __restrict__ out_att,
    float* __restrict__ natt, float* __restrict__ att_sums) {
  __shared__ bf16 As[2][32 * 256];
  __shared__ bf16 Bs[2][32 * 256];
  __shared__ float ssum[2][32];
  int tid = threadIdx.x, lane = tid & 63, wid = tid >> 6;
  int m0 = blockIdx.x * 32;
  if (tid < 64) ssum[tid >> 5][tid & 31] = 0.f;
  int lrow = lane & 15, lko = (lane >> 4) * 8, lr7 = lrow & 7;
  int r0 = (wid & 1) * 16, c0 = (wid >> 1) * 16;
  int scg = tid & 31;
  int srow = tid >> 5;
  const bf16* gA = Xb + (size_t)m0 * DD;
  const bf16* gB = nacb;
#pragma unroll
  for (int r = 0; r < 4; r++) {
    int row = r * 8 + srow;
    int cgg = (scg & 24) | ((scg & 7) ^ (row & 7));
    async_lds16(gA + (size_t)row * DD + cgg * 8, &As[0][r * 2048 + tid * 8]);
    async_lds16(gB + (size_t)row * DD + cgg * 8, &Bs[0][r * 2048 + tid * 8]);
  }
  floatx4 acc = {};
  int buf = 0;
  for (int k0 = 0; k0 < DD; k0 += 256) {
    __syncthreads();
    if (k0 + 256 < DD) {
#pragma unroll
      for (int r = 0; r < 4; r++) {
        int row = r * 8 + srow;
        int cgg = (scg & 24) | ((scg & 7) ^ (row & 7));
        async_lds16(gA + (size_t)row * DD + k0 + 256 + cgg * 8,
                    &As[buf ^ 1][r * 2048 + tid * 8]);
        async_lds16(gB + (size_t)row * DD + k0 + 256 + cgg * 8,
                    &Bs[buf ^ 1][r * 2048 + tid * 8]);
      }
    }
#pragma unroll
    for (int ks = 0; ks < 256; ks += 32) {
      int cg = (ks + lko) >> 3;
      int cgl = (cg & 24) | ((cg & 7) ^ lr7);
      bf16x8 a = *(const bf16x8*)(&As[buf][(r0 + lrow) * 256 + cgl * 8]);
      bf16x8 b = *(const bf16x8*)(&Bs[buf][(c0 + lrow) * 256 + cgl * 8]);
      acc = __builtin_amdgcn_mfma_f32_16x16x32_bf16(a, b, acc, 0, 0, 0);
    }
    buf ^= 1;
  }
  __syncthreads();
  int quad = lane >> 4;
  int nbase = m0 / TT;
  int c = c0 + lrow;
#pragma unroll
  for (int r = 0; r < 4; r++) {
    int row = m0 + r0 + quad * 4 + r;
    if (c < 22) {
      float iv = mode ? (1.f / (sqrtf(invn[row]) + 1e-9f)) : invn[row];
      float s = acc[r] * iv * 20.f;
      float sg = 1.f / (1.f + __expf(-s));
      int n_loc = row / TT - nbase;
      if (c < 21) out_frm[(size_t)row * 21 + c] = s;
      else out_att[row] = sg;
      natt[(size_t)row * 22 + c] = sg;
      atomicAdd(&ssum[n_loc][c], sg);
    }
  }
  __syncthreads();
  if (tid < 64) {
    int nl = tid >> 5, cs = tid & 31;
    int nn = nbase + nl;
    if (cs < 22 && nn < NB) {
      float v = ssum[nl][cs];
      if (v != 0.f) atomicAdd(&att_sums[nn * 22 + cs], v);
    }
  }
}

// ============ pred pass2 (4 t-chunks) ===========================================
__global__ __launch_bounds__(256) void k_pred_p2(
    const bf16* __restrict__ Xb, const float* __restrict__ natt,
    const float* __restrict__ sums, float* __restrict__ partF) {
  int n = blockIdx.x, dh = blockIdx.y, tc = blockIdx.z, tid = threadIdx.x;
  int d = dh * 1024 + tid * 4;
  int t0 = tc * PF_TCH;
  int tcnt = min(PF_TCH, TT - t0);
  __shared__ float sw[PF_TCH * 22];
  for (int i = tid; i < tcnt * 22; i += 256) {
    int c = i - (i / 22) * 22;
    sw[i] = natt[(size_t)(n * TT + t0) * 22 + i] / (sums[n * 22 + c] + 1e-5f);
  }
  __syncthreads();
  float ac[22][4] = {};
  const bf16* xrow = Xb + (size_t)n * TT * DD;
  bf16x4 xg = *(const bf16x4*)(xrow + (size_t)t0 * DD + d);
  for (int tt = 0; tt < tcnt; tt++) {
    bf16x4 x4 = xg;
    if (tt + 1 < tcnt) xg = *(const bf16x4*)(xrow + (size_t)(t0 + tt + 1) * DD + d);
    float xv[4] = {(float)x4[0], (float)x4[1], (float)x4[2], (float)x4[3]};
#pragma unroll
    for (int cidx = 0; cidx < 22; cidx++) {
      float w = sw[tt * 22 + cidx];
#pragma unroll
      for (int jj = 0; jj < 4; jj++) ac[cidx][jj] += w * xv[jj];
    }
  }
  float* pb = partF + ((size_t)(n * PF_CH + tc) * 22) * DD + d;
#pragma unroll
  for (int cidx = 0; cidx < 22; cidx++) {
    floatx4 v = {ac[cidx][0], ac[cidx][1], ac[cidx][2], ac[cidx][3]};
    *(floatx4*)(pb + (size_t)cidx * DD) = v;
  }
}

// ============ final scores + softmax (fused partF reduction) ====================
__global__ void k_pred_final(const float* __restrict__ partF, float* __restrict__ feats,
                             const float* __restrict__ nacf,
                             float* __restrict__ oca, float* __restrict__ ocw) {
  int n = blockIdx.x, tid = threadIdx.x, lane = tid & 63, wid = tid >> 6;
  float* fnw = feats + (size_t)n * 22 * DD;
  const float* pp = partF + ((size_t)n * PF_CH) * (22 * DD);
  for (int i = tid * 4; i < 22 * DD; i += 1024) {
    floatx4 s = {};
#pragma unroll
    for (int tc = 0; tc < PF_CH; tc++) {
      floatx4 v = *(const floatx4*)(pp + (size_t)tc * 22 * DD + i);
      s.x += v.x; s.y += v.y; s.z += v.z; s.w += v.w;
    }
    *(floatx4*)(fnw + i) = s;
  }
  __threadfence_block();
  __syncthreads();
  const float* fn = fnw;
  __shared__ float rnorm[22];
  __shared__ float scr[42];
  for (int r = wid; r < 22; r += 4) {
    const float* fv = fn + (size_t)r * DD;
    float s = 0.f;
    for (int i = lane * 4; i < DD; i += 256) {
      floatx4 v = *(const floatx4*)(fv + i);
      s += v.x * v.x + v.y * v.y + v.z * v.z + v.w * v.w;
    }
    s = wave_allreduce_sum(s);
    if (lane == 0) rnorm[r] = 1.f / (sqrtf(s) + 1e-9f);
  }
  __syncthreads();
  for (int idx = wid; idx < 42; idx += 4) {
    int c = (idx < 21) ? idx : (idx - 21);
    int fr = (idx < 21) ? c : 21;
    const float* fv = fn + (size_t)fr * DD;
    const float* av = nacf + (size_t)c * DD;
    float s = 0.f;
    for (int i = lane * 4; i < DD; i += 256) {
      floatx4 v = *(const floatx4*)(fv + i);
      floatx4 a = *(const floatx4*)(av + i);
      s += v.x * a.x + v.y * a.y + v.z * a.z + v.w * a.w;
    }
    s = wave_allreduce_sum(s);
    if (lane == 0) scr[idx] = s * 20.f * rnorm[fr];
  }
  __syncthreads();
  if (tid < 2) {
    int base = (tid == 0) ? 21 : 0;
    float* dst = ((tid == 0) ? oca : ocw) + (size_t)n * 21;
    float mx = scr[base];
    for (int c = 1; c < 21; c++) mx = fmaxf(mx, scr[base + c]);
    float se = 0.f;
    for (int c = 0; c < 21; c++) se += __expf(scr[base + c] - mx);
    float inv = 1.f / se;
    for (int c = 0; c < 21; c++) dst[c] = __expf(scr[base + c] - mx) * inv;
  }
}

extern "C" void kernel_launch(void* const* d_in, const int* in_sizes, int n_in,
                              void* d_out, int out_size, void* d_ws, size_t ws_size,
                              hipStream_t stream) {
  const float* x_in = (const float*)d_in[0];
  const float* W = (const float*)d_in[1];
  const float* bemb = (const float*)d_in[2];
  const float* mup = (const float*)d_in[3];
  const float* ac = (const float*)d_in[4];
  const float* fg = (const float*)d_in[5];
  float* out = (float*)d_out;

  char* ws = (char*)d_ws;
  bf16* Wt = (bf16*)ws;                       // 8,388,608
  bf16* Xb = (bf16*)(ws + 8388608);           // 49,283,072 (12032 rows)
  bf16* Rb = (bf16*)(ws + 57671680);          // 49,283,072
  bf16* Ab = (bf16*)(ws + 106954752);         // 49,283,072 (alias: part2 / partF)
  float* part2 = (float*)(ws + 106954752);    // 12.6 MB (EM phase, 12 chunks)
  float* partF = (float*)(ws + 106954752);    // 23.1 MB (pred phase, 4 chunks)
  bf16* nacb = (bf16*)(ws + 156237824);       // 131,072
  float* f = (float*)(ws + 156368896);
  float* nacf = f;                       // 45,056
  float* mu = nacf + 45056;              // 262,144
  float* nmu = mu + 262144;              // 262,144
  bf16* nmub = (bf16*)(nmu + 262144);    // 262,144 floats worth (1 MB)
  float* accS = nmu + 262144 + 262144;   // 262,144
  float* G = accS + 262144;              // 262,144
  float* z = G + 262144;                 // 96,000  [n][750][8]
  float* natt = z + 96000;               // 264,000
  float* feats = natt + 264000;          // 720,896
  float* invr = feats + 720896;          // 12,032
  float* rowsum = invr + 12032;          // 768 (zeroed)
  float* asums_o = rowsum + 768;         // 352 (zeroed)
  float* asums_m = asums_o + 352;        // 352 (zeroed)
  float* rowsq = asums_m + 352;          // 12,032 (zeroed)

  float* o_ca = out;
  float* o_cw = out + 336;
  float* o_att = out + 672;
  float* o_frm = out + 12672;
  float* m_ca = out + 264672;
  float* m_cw = out + 265008;
  float* m_att = out + 265344;
  float* m_frm = out + 277344;
  float* x_out = out + 529344;
  float* mu_out = out + 25105344;
  float* mup_out = out + 25367488;

  hipMemsetAsync(rowsum, 0, (768 + 352 + 352 + 12032) * sizeof(float), stream);
  hipMemsetAsync(nmub, 0, (size_t)NB * 16 * DD * sizeof(bf16), stream);
  k_prep<<<7264, 256, 0, stream>>>(W, Wt, ac, fg, nacf, nacb, mup, nmu, nmub, x_in, Ab);
  k_gemm<<<1504, 256, 0, stream>>>(Ab, Wt, bemb, x_out, Xb, rowsq);
  for (int it = 0; it < 5; it++) {
    bool last = (it == 4);
    k_em_iter<<<dim3(EM_CH, 16), 256, 0, stream>>>(Xb, nmub, rowsq, z, rowsum + it * 128, part2);
    k_mu_finish<<<128, 256, 0, stream>>>(part2, rowsum + it * 128, nullptr, mu,
                                         last ? mu_out : nullptr, nmu, nmub);
  }
  k_em_iter<<<dim3(EM_CH, 16), 256, 0, stream>>>(Xb, nmub, rowsq, z, rowsum + 5 * 128, part2);
  k_mu_finish<<<128, 256, 0, stream>>>(part2, nullptr, accS, nullptr, nullptr, nullptr, nullptr);
  k_wood_mupred<<<144, 256, 0, stream>>>(z, rowsum + 5 * 128, accS, mu, G, nmu, nacf, mup_out);
  k_rw_passC<<<dim3(16, 25), 256, 0, stream>>>(Xb, z, G, Rb, invr);
  // o-phase (on x)
  k_pred_p1<<<375, 256, 0, stream>>>(Xb, nacb, rowsq, 1, o_frm, o_att, natt, asums_o);
  k_pred_p2<<<dim3(16, 2, PF_CH), 256, 0, stream>>>(Xb, natt, asums_o, partF);
  k_pred_final<<<16, 256, 0, stream>>>(partF, feats, nacf, o_ca, o_cw);
  // m-phase (on refined)
  k_pred_p1<<<375, 256, 0, stream>>>(Rb, nacb, invr, 0, m_frm, m_att, natt, asums_m);
  k_pred_p2<<<dim3(16, 2, PF_CH), 256, 0, stream>>>(Rb, natt, asums_m, partF);
  k_pred_final<<<16, 256, 0, stream>>>(partF, feats, nacf, m_ca, m_cw);
}

// Round 9
// 847.794 us; speedup vs baseline: 1.0757x; 1.0757x over previous
//
#include <hip/hip_runtime.h>

#define NB 16
#define TT 750
#define DD 2048
#define KK 8
#define CC 21
#define NT 12000

// mu-accumulate t-chunking: 16 chunks of 47 rows (16*47 = 752 >= 750)
#define MU_CH 16
#define MU_TCH 47

typedef __bf16 bf16;
typedef __attribute__((ext_vector_type(4))) float floatx4;
typedef __attribute__((ext_vector_type(8))) __bf16 bf16x8;
typedef __attribute__((ext_vector_type(4))) __bf16 bf16x4;

__device__ __forceinline__ float wave_allreduce_sum(float v) {
#pragma unroll
  for (int m = 32; m > 0; m >>= 1) v += __shfl_xor(v, m, 64);
  return v;
}

__device__ __forceinline__ void async_lds16(const bf16* g, bf16* l) {
  __builtin_amdgcn_global_load_lds(
      (const __attribute__((address_space(1))) void*)(g),
      (__attribute__((address_space(3))) void*)(l), 16, 0, 0);
}

// ============ fused prep: W transpose+bf16 | ac_norm | mu_norm0 | x->bf16 =======
__global__ __launch_bounds__(256) void k_prep(
    const float* __restrict__ W, bf16* __restrict__ Wt,
    const float* __restrict__ ac, const float* __restrict__ fg,
    float* __restrict__ nacf, bf16* __restrict__ nacb,
    const float* __restrict__ mup, float* __restrict__ nmu, bf16* __restrict__ nmub,
    const float* __restrict__ x, bf16* __restrict__ Ab) {
  int b = blockIdx.x, tid = threadIdx.x;
  __shared__ float tile[32][33];
  __shared__ float sb[4];
  if (b < 4096) {
    int j0 = (b & 63) * 32, k0 = (b >> 6) * 32;
    int tx = tid & 31, ty = tid >> 5;
#pragma unroll
    for (int i = 0; i < 4; i++)
      tile[ty + 8 * i][tx] = W[(size_t)(k0 + ty + 8 * i) * DD + j0 + tx];
    __syncthreads();
#pragma unroll
    for (int i = 0; i < 4; i++)
      Wt[(size_t)(j0 + ty + 8 * i) * DD + k0 + tx] = (bf16)tile[tx][ty + 8 * i];
    return;
  }
  if (b < 4128) {
    int r = b - 4096;
    int d0 = tid * 8;
    if (r >= 22) {
#pragma unroll
      for (int j = 0; j < 8; j++) nacb[(size_t)r * DD + d0 + j] = (bf16)0.f;
      return;
    }
    const float* src = (r < 21) ? (ac + (size_t)r * DD) : fg;
    float v[8];
    floatx4 a = *(const floatx4*)(src + d0);
    floatx4 c = *(const floatx4*)(src + d0 + 4);
    v[0]=a.x; v[1]=a.y; v[2]=a.z; v[3]=a.w; v[4]=c.x; v[5]=c.y; v[6]=c.z; v[7]=c.w;
    float ss = 0.f;
#pragma unroll
    for (int j = 0; j < 8; j++) ss += v[j] * v[j];
    ss = wave_allreduce_sum(ss);
    int lane = tid & 63, wid = tid >> 6;
    if (lane == 0) sb[wid] = ss;
    __syncthreads();
    float inv = 1.f / (sqrtf(sb[0] + sb[1] + sb[2] + sb[3]) + 1e-9f);
#pragma unroll
    for (int j = 0; j < 8; j++) {
      float nv = v[j] * inv;
      nacf[(size_t)r * DD + d0 + j] = nv;
      nacb[(size_t)r * DD + d0 + j] = (bf16)nv;
    }
    return;
  }
  if (b < 4256) {
    int bb = b - 4128;  // n*8+k
    int n = bb >> 3, k = bb & 7;
    int lane = tid & 63, wid = tid >> 6;
    const float* p = mup + (size_t)k * DD + tid * 8;
    float v[8];
    floatx4 a = *(const floatx4*)p;
    floatx4 c = *(const floatx4*)(p + 4);
    v[0]=a.x; v[1]=a.y; v[2]=a.z; v[3]=a.w; v[4]=c.x; v[5]=c.y; v[6]=c.z; v[7]=c.w;
    float ss = 0.f;
#pragma unroll
    for (int j = 0; j < 8; j++) ss += v[j] * v[j];
    ss = wave_allreduce_sum(ss);
    if (lane == 0) sb[wid] = ss;
    __syncthreads();
    float inv = 1.f / (sqrtf(sb[0] + sb[1] + sb[2] + sb[3]) + 1e-9f);
    float* q = nmu + (size_t)bb * DD + tid * 8;
    bf16* qb = nmub + (size_t)(n * 16 + k) * DD + tid * 8;
#pragma unroll
    for (int j = 0; j < 8; j++) {
      float nv = v[j] * inv;
      q[j] = nv;
      qb[j] = (bf16)nv;
    }
    return;
  }
  int unit0 = (b - 4256) * 4;
#pragma unroll
  for (int u = 0; u < 4; u++) {
    size_t base = ((size_t)(unit0 + u) * 256 + tid) * 8;
    int row = (int)(base >> 11);
    bf16x8 o = {};
    if (row < NT) {
      floatx4 a = *(const floatx4*)(x + base);
      floatx4 c = *(const floatx4*)(x + base + 4);
      o[0]=(bf16)a.x; o[1]=(bf16)a.y; o[2]=(bf16)a.z; o[3]=(bf16)a.w;
      o[4]=(bf16)c.x; o[5]=(bf16)c.y; o[6]=(bf16)c.z; o[7]=(bf16)c.w;
    }
    *(bf16x8*)(Ab + base) = o;
  }
}

// ============ embedding GEMM (round-5 structure + XCD m-band swizzle) ===========
__global__ __launch_bounds__(256) void k_gemm(
    const bf16* __restrict__ Ab, const bf16* __restrict__ Bt,
    const float* __restrict__ bias,
    float* __restrict__ Cout, bf16* __restrict__ Cb, float* __restrict__ rowsq) {
  __shared__ bf16 As[128 * 64];
  __shared__ bf16 Bs[128 * 64];
  int tid = threadIdx.x;
  int bid = blockIdx.x;
  int wid2 = (bid & 7) * 188 + (bid >> 3);  // XCD x owns wid2 in [188x, 188(x+1))
  int mt = wid2 >> 4, nt = wid2 & 15;
  int m0 = mt * 128, n0 = nt * 128;
  int wid = tid >> 6, lane = tid & 63;
  int wm = (wid >> 1) * 64, wn = (wid & 1) * 64;
  int lrow = lane & 15, lko = (lane >> 4) * 8;
  int lr7 = lrow & 7;
  floatx4 acc[4][4] = {};
  int crow = tid >> 3;
  int jg = ((tid & 7) ^ (crow & 7)) * 8;
  const bf16* gA = Ab + (size_t)(m0 + crow) * DD + jg;
  const bf16* gB = Bt + (size_t)(n0 + crow) * DD + jg;
  bf16* lA = As + tid * 8;
  bf16* lB = Bs + tid * 8;
  for (int k0 = 0; k0 < DD; k0 += 64) {
#pragma unroll
    for (int s = 0; s < 4; s++)
      async_lds16(gA + (size_t)(32 * s) * DD + k0, lA + 2048 * s);
#pragma unroll
    for (int s = 0; s < 4; s++)
      async_lds16(gB + (size_t)(32 * s) * DD + k0, lB + 2048 * s);
    __syncthreads();
#pragma unroll
    for (int ks = 0; ks < 64; ks += 32) {
      bf16x8 af[4], bfr[4];
#pragma unroll
      for (int i = 0; i < 4; i++) {
        int sw = (((ks + lko) >> 3) ^ lr7) * 8;
        af[i] = *(const bf16x8*)(As + (wm + i * 16 + lrow) * 64 + sw);
      }
#pragma unroll
      for (int jj = 0; jj < 4; jj++) {
        int sw = (((ks + lko) >> 3) ^ lr7) * 8;
        bfr[jj] = *(const bf16x8*)(Bs + (wn + jj * 16 + lrow) * 64 + sw);
      }
#pragma unroll
      for (int i = 0; i < 4; i++)
#pragma unroll
        for (int jj = 0; jj < 4; jj++)
          acc[i][jj] = __builtin_amdgcn_mfma_f32_16x16x32_bf16(af[i], bfr[jj], acc[i][jj], 0, 0, 0);
    }
    __syncthreads();
  }
  int quad = lane >> 4;
  float bv[4];
#pragma unroll
  for (int jj = 0; jj < 4; jj++) bv[jj] = bias[n0 + wn + jj * 16 + lrow];
#pragma unroll
  for (int i = 0; i < 4; i++) {
#pragma unroll
    for (int r = 0; r < 4; r++) {
      int row = m0 + wm + i * 16 + quad * 4 + r;
      bool ok = (row < NT);
      float sq = 0.f;
#pragma unroll
      for (int jj = 0; jj < 4; jj++) {
        int col = n0 + wn + jj * 16 + lrow;
        float v = acc[i][jj][r] + bv[jj];
        v = fmaxf(v, 0.f);
        if (ok) {
          Cout[(size_t)row * DD + col] = v;
          Cb[(size_t)row * DD + col] = (bf16)v;
        }
        sq += v * v;
      }
#pragma unroll
      for (int m = 1; m < 16; m <<= 1) sq += __shfl_xor(sq, m, 64);
      if (ok && lrow == 0) atomicAdd(&rowsq[row], sq);
    }
  }
}

// ============ EM score pass: MFMA [64t x 16k], BK=256 deep-pipelined staging =====
__global__ __launch_bounds__(256) void k_score(
    const bf16* __restrict__ Xb, const bf16* __restrict__ nmub,
    const float* __restrict__ rowsq,
    float* __restrict__ z, float* __restrict__ rowsum) {
  __shared__ bf16 As[2][64 * 256];
  __shared__ bf16 Bs[2][16 * 256];
  int tid = threadIdx.x, lane = tid & 63, w = tid >> 6;
  int m0 = blockIdx.x * 64, n = blockIdx.y;
  int lrow = lane & 15, lko = (lane >> 4) * 8, lr7 = lrow & 7;
  int scg = tid & 31;
  int srow = tid >> 5;
  const bf16* gXn = Xb + (size_t)(n * TT + m0) * DD;
  const bf16* gBn = nmub + (size_t)(n * 16) * DD;
#pragma unroll
  for (int r = 0; r < 8; r++) {
    int row = r * 8 + srow;
    int cgg = (scg & 24) | ((scg & 7) ^ (row & 7));
    async_lds16(gXn + (size_t)row * DD + cgg * 8, &As[0][r * 2048 + tid * 8]);
  }
#pragma unroll
  for (int r = 0; r < 2; r++) {
    int row = r * 8 + srow;
    int cgg = (scg & 24) | ((scg & 7) ^ (row & 7));
    async_lds16(gBn + (size_t)row * DD + cgg * 8, &Bs[0][r * 2048 + tid * 8]);
  }
  floatx4 acc = {};
  int buf = 0;
  for (int k0 = 0; k0 < DD; k0 += 256) {
    __syncthreads();
    if (k0 + 256 < DD) {
#pragma unroll
      for (int r = 0; r < 8; r++) {
        int row = r * 8 + srow;
        int cgg = (scg & 24) | ((scg & 7) ^ (row & 7));
        async_lds16(gXn + (size_t)row * DD + k0 + 256 + cgg * 8,
                    &As[buf ^ 1][r * 2048 + tid * 8]);
      }
#pragma unroll
      for (int r = 0; r < 2; r++) {
        int row = r * 8 + srow;
        int cgg = (scg & 24) | ((scg & 7) ^ (row & 7));
        async_lds16(gBn + (size_t)row * DD + k0 + 256 + cgg * 8,
                    &Bs[buf ^ 1][r * 2048 + tid * 8]);
      }
    }
    int arow = w * 16 + lrow;
#pragma unroll
    for (int ks = 0; ks < 256; ks += 32) {
      int cg = (ks + lko) >> 3;
      int cgl = (cg & 24) | ((cg & 7) ^ lr7);
      bf16x8 a = *(const bf16x8*)(&As[buf][arow * 256 + cgl * 8]);
      bf16x8 b = *(const bf16x8*)(&Bs[buf][lrow * 256 + cgl * 8]);
      acc = __builtin_amdgcn_mfma_f32_16x16x32_bf16(a, b, acc, 0, 0, 0);
    }
    buf ^= 1;
  }
  int quad = lane >> 4;
  int k = lrow;
  float pacc = 0.f;
#pragma unroll
  for (int r = 0; r < 4; r++) {
    int trow = m0 + w * 16 + quad * 4 + r;
    bool valid = (trow < TT);
    float rq = valid ? rowsq[n * TT + trow] : 1.f;
    float s = acc[r] * (5.f / (sqrtf(rq) + 1e-9f));
    float mx = s;
    mx = fmaxf(mx, __shfl_xor(mx, 1, 64));
    mx = fmaxf(mx, __shfl_xor(mx, 2, 64));
    mx = fmaxf(mx, __shfl_xor(mx, 4, 64));
    float e = __expf(s - mx);
    float se = e;
    se += __shfl_xor(se, 1, 64);
    se += __shfl_xor(se, 2, 64);
    se += __shfl_xor(se, 4, 64);
    float zz = e / se;
    zz = (valid && k < 8) ? zz : 0.f;
    if (valid && k < 8) z[(size_t)(n * TT + trow) * 8 + k] = zz;
    pacc += zz;
  }
  pacc += __shfl_xor(pacc, 16, 64);
  pacc += __shfl_xor(pacc, 32, 64);
  if (lane < 8) atomicAdd(&rowsum[n * 8 + lane], pacc);
}

// ============ EM accumulate: mu_part = z @ X =====================================
__global__ __launch_bounds__(256) void k_mu_accum(
    const bf16* __restrict__ Xb, const float* __restrict__ z,
    float* __restrict__ part2) {
  int n = blockIdx.x, tc = blockIdx.y, tid = threadIdx.x;
  int t0 = tc * MU_TCH;
  int tcnt = min(MU_TCH, TT - t0);
  __shared__ float zs[MU_TCH * 8];
  for (int i = tid; i < tcnt * 8; i += 256) zs[i] = z[(size_t)(n * TT + t0) * 8 + i];
  __syncthreads();
  float acc[8][8] = {};
  const bf16* xp = Xb + (size_t)(n * TT + t0) * DD + tid * 8;
  bf16x8 x0 = *(const bf16x8*)xp;
  bf16x8 x1 = (tcnt > 1) ? *(const bf16x8*)(xp + DD) : x0;
  for (int tt = 0; tt < tcnt; tt++) {
    bf16x8 cur = x0;
    x0 = x1;
    if (tt + 2 < tcnt) x1 = *(const bf16x8*)(xp + (size_t)(tt + 2) * DD);
    float xv[8];
#pragma unroll
    for (int j = 0; j < 8; j++) xv[j] = (float)cur[j];
    floatx4 za = *(const floatx4*)&zs[tt * 8];
    floatx4 zb4 = *(const floatx4*)&zs[tt * 8 + 4];
    float zk[8] = {za.x, za.y, za.z, za.w, zb4.x, zb4.y, zb4.z, zb4.w};
#pragma unroll
    for (int k = 0; k < 8; k++)
#pragma unroll
      for (int j = 0; j < 8; j++) acc[k][j] += zk[k] * xv[j];
  }
  float* pb = part2 + ((size_t)(tc * 16 + n) * 8) * DD + tid * 8;
#pragma unroll
  for (int k = 0; k < 8; k++) {
    floatx4 lo = {acc[k][0], acc[k][1], acc[k][2], acc[k][3]};
    floatx4 hi = {acc[k][4], acc[k][5], acc[k][6], acc[k][7]};
    *(floatx4*)(pb + (size_t)k * DD) = lo;
    *(floatx4*)(pb + (size_t)k * DD + 4) = hi;
  }
}

// ============ EM finish =========================================================
__global__ void k_mu_finish(const float* __restrict__ part2, const float* __restrict__ rs,
                            float* __restrict__ accS_raw, float* __restrict__ mu_ws,
                            float* __restrict__ mu_out, float* __restrict__ nmu_out,
                            bf16* __restrict__ nmub) {
  int b = blockIdx.x;  // n*8+k
  int n = b >> 3, k = b & 7;
  int tid = threadIdx.x, lane = tid & 63, wid = tid >> 6;
  int d0 = tid * 8;
  float s[8] = {};
#pragma unroll 4
  for (int c = 0; c < MU_CH; c++) {
    const float* p = part2 + ((size_t)(c * 16 + n) * 8 + k) * DD + d0;
    floatx4 a = *(const floatx4*)p;
    floatx4 cc = *(const floatx4*)(p + 4);
    s[0] += a.x; s[1] += a.y; s[2] += a.z; s[3] += a.w;
    s[4] += cc.x; s[5] += cc.y; s[6] += cc.z; s[7] += cc.w;
  }
  if (accS_raw != nullptr) {
#pragma unroll
    for (int j = 0; j < 8; j++) accS_raw[(size_t)b * DD + d0 + j] = s[j];
    return;
  }
  float invr = 1.f / (rs[b] + 1e-9f);
  float m[8];
#pragma unroll
  for (int j = 0; j < 8; j++) m[j] = s[j] * invr;
#pragma unroll
  for (int j = 0; j < 8; j++) mu_ws[(size_t)b * DD + d0 + j] = m[j];
  if (mu_out != nullptr) {
#pragma unroll
    for (int j = 0; j < 8; j++) mu_out[(size_t)b * DD + d0 + j] = m[j];
  }
  float ss = 0.f;
#pragma unroll
  for (int j = 0; j < 8; j++) ss += m[j] * m[j];
  ss = wave_allreduce_sum(ss);
  __shared__ float sb[4];
  if (lane == 0) sb[wid] = ss;
  __syncthreads();
  float inv = 1.f / (sqrtf(sb[0] + sb[1] + sb[2] + sb[3]) + 1e-9f);
  bf16* qb = nmub + (size_t)(n * 16 + k) * DD + d0;
#pragma unroll
  for (int j = 0; j < 8; j++) {
    float nv = m[j] * inv;
    nmu_out[(size_t)b * DD + d0 + j] = nv;
    qb[j] = (bf16)nv;
  }
}

// ============ Woodbury + mu_pred ================================================
__global__ void k_wood_mupred(const float* __restrict__ z, const float* __restrict__ rowsum,
                              const float* __restrict__ S, const float* __restrict__ mu,
                              float* __restrict__ G,
                              const float* __restrict__ nmu, const float* __restrict__ nacf,
                              float* __restrict__ mupred) {
  int tid = threadIdx.x;
  if (blockIdx.x >= 16) {
    int b = blockIdx.x - 16;
    int lane = tid & 63, wid = tid >> 6;
    const float* v = nmu + (size_t)b * DD;
    __shared__ float scr[21];
    for (int c = wid; c < 21; c += 4) {
      const float* a = nacf + (size_t)c * DD;
      float s = 0.f;
      for (int i = lane * 4; i < DD; i += 256) {
        floatx4 vv = *(const floatx4*)(v + i);
        floatx4 aa = *(const floatx4*)(a + i);
        s += vv.x * aa.x + vv.y * aa.y + vv.z * aa.z + vv.w * aa.w;
      }
      s = wave_allreduce_sum(s);
      if (lane == 0) scr[c] = s * 20.f;
    }
    __syncthreads();
    if (tid == 0) {
      float mx = scr[0];
      for (int c = 1; c < 21; c++) mx = fmaxf(mx, scr[c]);
      float se = 0.f;
      for (int c = 0; c < 21; c++) se += __expf(scr[c] - mx);
      float inv = 1.f / se;
      for (int c = 0; c < 21; c++) mupred[(size_t)b * 21 + c] = __expf(scr[c] - mx) * inv;
    }
    return;
  }
  int n = blockIdx.x;
  __shared__ float VU[8][8];
  __shared__ float Mi[8][8];
  __shared__ float invrs[8];
  __shared__ float vus[64][4];
  if (tid < 8) invrs[tid] = 1.f / (rowsum[n * 8 + tid] + 1e-9f);
  {
    int pr = tid >> 2, sl = tid & 3;
    int jj = pr >> 3, kk = pr & 7;
    float s = 0.f;
    for (int t = sl; t < TT; t += 4) {
      const float* zp = z + (size_t)(n * TT + t) * 8;
      s += zp[jj] * zp[kk];
    }
    vus[pr][sl] = s;
  }
  __syncthreads();
  if (tid < 64)
    VU[tid >> 3][tid & 7] =
        (vus[tid][0] + vus[tid][1] + vus[tid][2] + vus[tid][3]) * invrs[tid >> 3];
  __syncthreads();
  if (tid == 0) {
    float M[8][16];
    for (int i = 0; i < 8; i++)
      for (int jj = 0; jj < 8; jj++) {
        M[i][jj] = ((i == jj) ? 1.f : 0.f) - 0.25f * VU[i][jj];
        M[i][8 + jj] = (i == jj) ? 1.f : 0.f;
      }
    for (int c = 0; c < 8; c++) {
      float pv = 1.f / M[c][c];
      for (int jj = 0; jj < 16; jj++) M[c][jj] *= pv;
      for (int rr = 0; rr < 8; rr++)
        if (rr != c) {
          float f = M[rr][c];
          for (int jj = 0; jj < 16; jj++) M[rr][jj] -= f * M[c][jj];
        }
    }
    for (int i = 0; i < 8; i++)
      for (int jj = 0; jj < 8; jj++) Mi[i][jj] = M[i][8 + jj];
  }
  __syncthreads();
  const float* mun = mu + (size_t)n * 8 * DD;
  const float* Sn = S + (size_t)n * 8 * DD;
  float* Gn = G + (size_t)n * 8 * DD;
  for (int d = tid; d < DD; d += 256) {
    float m[8], P[8];
#pragma unroll
    for (int k = 0; k < 8; k++) m[k] = mun[k * DD + d];
#pragma unroll
    for (int k = 0; k < 8; k++) {
      float s = 0.f;
#pragma unroll
      for (int jj = 0; jj < 8; jj++) s += VU[k][jj] * m[jj];
      P[k] = 0.5f * s + Sn[k * DD + d] * invrs[k];
    }
#pragma unroll
    for (int jj = 0; jj < 8; jj++) {
      float s = 0.f;
#pragma unroll
      for (int k = 0; k < 8; k++) s += Mi[jj][k] * P[k];
      Gn[jj * DD + d] = 0.5f * (0.5f * m[jj] + 0.25f * s);
    }
  }
}

// ============ RW pass ===========================================================
__global__ __launch_bounds__(256) void k_rw_passC(
    const bf16* __restrict__ Xb, const float* __restrict__ z,
    const float* __restrict__ G, bf16* __restrict__ refb,
    float* __restrict__ invr) {
  int n = blockIdx.x, ch = blockIdx.y, tid = threadIdx.x;
  int lane = tid & 63, wid = tid >> 6;
  int d0 = tid * 8;
  int t0 = ch * 30;
  const float* Gn = G + (size_t)n * 8 * DD;
  float gr[8][8];
#pragma unroll
  for (int k = 0; k < 8; k++) {
    floatx4 a = *(const floatx4*)(Gn + k * DD + d0);
    floatx4 b = *(const floatx4*)(Gn + k * DD + d0 + 4);
    gr[k][0]=a.x; gr[k][1]=a.y; gr[k][2]=a.z; gr[k][3]=a.w;
    gr[k][4]=b.x; gr[k][5]=b.y; gr[k][6]=b.z; gr[k][7]=b.w;
  }
  __shared__ float red[30][4];
  const bf16* xrow = Xb + (size_t)n * TT * DD;
  bf16x8 xg = *(const bf16x8*)(xrow + (size_t)t0 * DD + d0);
  for (int tt = 0; tt < 30; tt++) {
    int t = t0 + tt;
    bf16x8 x8 = xg;
    if (tt + 1 < 30) xg = *(const bf16x8*)(xrow + (size_t)(t + 1) * DD + d0);
    const float* zp = z + (size_t)(n * TT + t) * 8;
    floatx4 za = *(const floatx4*)zp;
    floatx4 zb4 = *(const floatx4*)(zp + 4);
    float zt[8] = {za.x, za.y, za.z, za.w, zb4.x, zb4.y, zb4.z, zb4.w};
    float r[8];
#pragma unroll
    for (int j = 0; j < 8; j++) {
      float s = 0.5f * (float)x8[j];
#pragma unroll
      for (int k = 0; k < 8; k++) s += zt[k] * gr[k][j];
      r[j] = s;
    }
    bf16x8 ro;
#pragma unroll
    for (int j = 0; j < 8; j++) ro[j] = (bf16)r[j];
    *(bf16x8*)(refb + (size_t)(n * TT + t) * DD + d0) = ro;
    float ss = 0.f;
#pragma unroll
    for (int j = 0; j < 8; j++) ss += r[j] * r[j];
    ss = wave_allreduce_sum(ss);
    if (lane == 0) red[tt][wid] = ss;
  }
  __syncthreads();
  if (tid < 30) {
    float tot = red[tid][0] + red[tid][1] + red[tid][2] + red[tid][3];
    invr[n * TT + t0 + tid] = 1.f / (sqrtf(tot) + 1e-9f);
  }
}

// ============ pred pass1 (BK=256 deep-pipelined staging) ========================
__global__ __launch_bounds__(256) void k_pred_p1(
    const bf16* __restrict__ Xb, const bf16* __restrict__ nacb,
    const float* __restrict__ invn, int mode,
    float* __restrict__ out_frm, float* __restrict__ out_att,
    float* __restrict__ natt, float* __restrict__ att_sums) {
  __shared__ bf16 As[2][32 * 256];
  __shared__ bf16 Bs[2][32 * 256];
  __shared__ float ssum[2][32];
  int tid = threadIdx.x, lane = tid & 63, wid = tid >> 6;
  int m0 = blockIdx.x * 32;
  if (tid < 64) ssum[tid >> 5][tid & 31] = 0.f;
  int lrow = lane & 15, lko = (lane >> 4) * 8, lr7 = lrow & 7;
  int r0 = (wid & 1) * 16, c0 = (wid >> 1) * 16;
  int scg = tid & 31;
  int srow = tid >> 5;
  const bf16* gA = Xb + (size_t)m0 * DD;
  const bf16* gB = nacb;
#pragma unroll
  for (int r = 0; r < 4; r++) {
    int row = r * 8 + srow;
    int cgg = (scg & 24) | ((scg & 7) ^ (row & 7));
    async_lds16(gA + (size_t)row * DD + cgg * 8, &As[0][r * 2048 + tid * 8]);
    async_lds16(gB + (size_t)row * DD + cgg * 8, &Bs[0][r * 2048 + tid * 8]);
  }
  floatx4 acc = {};
  int buf = 0;
  for (int k0 = 0; k0 < DD; k0 += 256) {
    __syncthreads();
    if (k0 + 256 < DD) {
#pragma unroll
      for (int r = 0; r < 4; r++) {
        int row = r * 8 + srow;
        int cgg = (scg & 24) | ((scg & 7) ^ (row & 7));
        async_lds16(gA + (size_t)row * DD + k0 + 256 + cgg * 8,
                    &As[buf ^ 1][r * 2048 + tid * 8]);
        async_lds16(gB + (size_t)row * DD + k0 + 256 + cgg * 8,
                    &Bs[buf ^ 1][r * 2048 + tid * 8]);
      }
    }
#pragma unroll
    for (int ks = 0; ks < 256; ks += 32) {
      int cg = (ks + lko) >> 3;
      int cgl = (cg & 24) | ((cg & 7) ^ lr7);
      bf16x8 a = *(const bf16x8*)(&As[buf][(r0 + lrow) * 256 + cgl * 8]);
      bf16x8 b = *(const bf16x8*)(&Bs[buf][(c0 + lrow) * 256 + cgl * 8]);
      acc = __builtin_amdgcn_mfma_f32_16x16x32_bf16(a, b, acc, 0, 0, 0);
    }
    buf ^= 1;
  }
  __syncthreads();
  int quad = lane >> 4;
  int nbase = m0 / TT;
  int c = c0 + lrow;
#pragma unroll
  for (int r = 0; r < 4; r++) {
    int row = m0 + r0 + quad * 4 + r;
    if (c < 22) {
      float iv = mode ? (1.f / (sqrtf(invn[row]) + 1e-9f)) : invn[row];
      float s = acc[r] * iv * 20.f;
      float sg = 1.f / (1.f + __expf(-s));
      int n_loc = row / TT - nbase;
      if (c < 21) out_frm[(size_t)row * 21 + c] = s;
      else out_att[row] = sg;
      natt[(size_t)row * 22 + c] = sg;
      atomicAdd(&ssum[n_loc][c], sg);
    }
  }
  __syncthreads();
  if (tid < 64) {
    int nl = tid >> 5, cs = tid & 31;
    int nn = nbase + nl;
    if (cs < 22 && nn < NB) {
      float v = ssum[nl][cs];
      if (v != 0.f) atomicAdd(&att_sums[nn * 22 + cs], v);
    }
  }
}

// ============ pred pass2 (8 t-chunks of 94) =====================================
__global__ __launch_bounds__(256) void k_pred_p2(
    const bf16* __restrict__ Xb, const float* __restrict__ natt,
    const float* __restrict__ sums, float* __restrict__ partF) {
  int n = blockIdx.x, dh = blockIdx.y, tc = blockIdx.z, tid = threadIdx.x;
  int d = dh * 1024 + tid * 4;
  int t0 = tc * 94;
  int tcnt = min(94, TT - t0);
  __shared__ float sw[94 * 22];
  for (int i = tid; i < tcnt * 22; i += 256) {
    int c = i - (i / 22) * 22;
    sw[i] = natt[(size_t)(n * TT + t0) * 22 + i] / (sums[n * 22 + c] + 1e-5f);
  }
  __syncthreads();
  float ac[22][4] = {};
  const bf16* xrow = Xb + (size_t)n * TT * DD;
  bf16x4 xg = *(const bf16x4*)(xrow + (size_t)t0 * DD + d);
  for (int tt = 0; tt < tcnt; tt++) {
    bf16x4 x4 = xg;
    if (tt + 1 < tcnt) xg = *(const bf16x4*)(xrow + (size_t)(t0 + tt + 1) * DD + d);
    float xv[4] = {(float)x4[0], (float)x4[1], (float)x4[2], (float)x4[3]};
#pragma unroll
    for (int cidx = 0; cidx < 22; cidx++) {
      float w = sw[tt * 22 + cidx];
#pragma unroll
      for (int jj = 0; jj < 4; jj++) ac[cidx][jj] += w * xv[jj];
    }
  }
  float* pb = partF + ((size_t)(n * 8 + tc) * 22) * DD + d;
#pragma unroll
  for (int cidx = 0; cidx < 22; cidx++) {
    floatx4 v = {ac[cidx][0], ac[cidx][1], ac[cidx][2], ac[cidx][3]};
    *(floatx4*)(pb + (size_t)cidx * DD) = v;
  }
}

// ============ reduce feats partials (full-BW grid) ==============================
__global__ void k_feat_finish(const float* __restrict__ partF, float* __restrict__ feats) {
  int idx = blockIdx.x * 256 + threadIdx.x;
  if (idx >= NB * 22 * DD) return;
  int n = idx / (22 * DD);
  int rem = idx - n * (22 * DD);
  const float* p = partF + ((size_t)n * 8) * (22 * DD) + rem;
  float s = 0.f;
#pragma unroll
  for (int tc = 0; tc < 8; tc++) s += p[(size_t)tc * 22 * DD];
  feats[idx] = s;
}

// ============ final scores + softmax ============================================
__global__ void k_pred_final(const float* __restrict__ feats, const float* __restrict__ nacf,
                             float* __restrict__ oca, float* __restrict__ ocw) {
  int n = blockIdx.x, tid = threadIdx.x, lane = tid & 63, wid = tid >> 6;
  const float* fn = feats + (size_t)n * 22 * DD;
  __shared__ float rnorm[22];
  __shared__ float scr[42];
  for (int r = wid; r < 22; r += 4) {
    const float* fv = fn + (size_t)r * DD;
    float s = 0.f;
    for (int i = lane * 4; i < DD; i += 256) {
      floatx4 v = *(const floatx4*)(fv + i);
      s += v.x * v.x + v.y * v.y + v.z * v.z + v.w * v.w;
    }
    s = wave_allreduce_sum(s);
    if (lane == 0) rnorm[r] = 1.f / (sqrtf(s) + 1e-9f);
  }
  __syncthreads();
  for (int idx = wid; idx < 42; idx += 4) {
    int c = (idx < 21) ? idx : (idx - 21);
    int fr = (idx < 21) ? c : 21;
    const float* fv = fn + (size_t)fr * DD;
    const float* av = nacf + (size_t)c * DD;
    float s = 0.f;
    for (int i = lane * 4; i < DD; i += 256) {
      floatx4 v = *(const floatx4*)(fv + i);
      floatx4 a = *(const floatx4*)(av + i);
      s += v.x * a.x + v.y * a.y + v.z * a.z + v.w * a.w;
    }
    s = wave_allreduce_sum(s);
    if (lane == 0) scr[idx] = s * 20.f * rnorm[fr];
  }
  __syncthreads();
  if (tid < 2) {
    int base = (tid == 0) ? 21 : 0;
    float* dst = ((tid == 0) ? oca : ocw) + (size_t)n * 21;
    float mx = scr[base];
    for (int c = 1; c < 21; c++) mx = fmaxf(mx, scr[base + c]);
    float se = 0.f;
    for (int c = 0; c < 21; c++) se += __expf(scr[base + c] - mx);
    float inv = 1.f / se;
    for (int c = 0; c < 21; c++) dst[c] = __expf(scr[base + c] - mx) * inv;
  }
}

extern "C" void kernel_launch(void* const* d_in, const int* in_sizes, int n_in,
                              void* d_out, int out_size, void* d_ws, size_t ws_size,
                              hipStream_t stream) {
  const float* x_in = (const float*)d_in[0];
  const float* W = (const float*)d_in[1];
  const float* bemb = (const float*)d_in[2];
  const float* mup = (const float*)d_in[3];
  const float* ac = (const float*)d_in[4];
  const float* fg = (const float*)d_in[5];
  float* out = (float*)d_out;

  char* ws = (char*)d_ws;
  bf16* Wt = (bf16*)ws;                       // 8,388,608
  bf16* Xb = (bf16*)(ws + 8388608);           // 49,283,072 (12032 rows)
  bf16* Rb = (bf16*)(ws + 57671680);          // 49,283,072
  bf16* Ab = (bf16*)(ws + 106954752);         // 49,283,072 (alias: part2 / partF)
  float* part2 = (float*)(ws + 106954752);    // 16.7 MB (EM phase, 16 chunks)
  float* partF = (float*)(ws + 106954752);    // 11.5 MB (pred phase, 8 chunks)
  bf16* nacb = (bf16*)(ws + 156237824);       // 131,072
  float* f = (float*)(ws + 156368896);
  float* nacf = f;                       // 45,056
  float* mu = nacf + 45056;              // 262,144
  float* nmu = mu + 262144;              // 262,144
  bf16* nmub = (bf16*)(nmu + 262144);    // 262,144 floats worth (1 MB)
  float* accS = nmu + 262144 + 262144;   // 262,144
  float* G = accS + 262144;              // 262,144
  float* z = G + 262144;                 // 96,000  [n][750][8]
  float* natt = z + 96000;               // 264,000
  float* feats = natt + 264000;          // 720,896
  float* invr = feats + 720896;          // 12,032
  float* rowsum = invr + 12032;          // 768 (zeroed)
  float* asums_o = rowsum + 768;         // 352 (zeroed)
  float* asums_m = asums_o + 352;        // 352 (zeroed)
  float* rowsq = asums_m + 352;          // 12,032 (zeroed)

  float* o_ca = out;
  float* o_cw = out + 336;
  float* o_att = out + 672;
  float* o_frm = out + 12672;
  float* m_ca = out + 264672;
  float* m_cw = out + 265008;
  float* m_att = out + 265344;
  float* m_frm = out + 277344;
  float* x_out = out + 529344;
  float* mu_out = out + 25105344;
  float* mup_out = out + 25367488;

  hipMemsetAsync(rowsum, 0, (768 + 352 + 352 + 12032) * sizeof(float), stream);
  hipMemsetAsync(nmub, 0, (size_t)NB * 16 * DD * sizeof(bf16), stream);
  k_prep<<<7264, 256, 0, stream>>>(W, Wt, ac, fg, nacf, nacb, mup, nmu, nmub, x_in, Ab);
  k_gemm<<<1504, 256, 0, stream>>>(Ab, Wt, bemb, x_out, Xb, rowsq);
  for (int it = 0; it < 5; it++) {
    bool last = (it == 4);
    k_score<<<dim3(12, 16), 256, 0, stream>>>(Xb, nmub, rowsq, z, rowsum + it * 128);
    k_mu_accum<<<dim3(16, MU_CH), 256, 0, stream>>>(Xb, z, part2);
    k_mu_finish<<<128, 256, 0, stream>>>(part2, rowsum + it * 128, nullptr, mu,
                                         last ? mu_out : nullptr, nmu, nmub);
  }
  k_score<<<dim3(12, 16), 256, 0, stream>>>(Xb, nmub, rowsq, z, rowsum + 5 * 128);
  k_mu_accum<<<dim3(16, MU_CH), 256, 0, stream>>>(Xb, z, part2);
  k_mu_finish<<<128, 256, 0, stream>>>(part2, nullptr, accS, nullptr, nullptr, nullptr, nullptr);
  k_wood_mupred<<<144, 256, 0, stream>>>(z, rowsum + 5 * 128, accS, mu, G, nmu, nacf, mup_out);
  k_rw_passC<<<dim3(16, 25), 256, 0, stream>>>(Xb, z, G, Rb, invr);
  // o-phase (on x)
  k_pred_p1<<<375, 256, 0, stream>>>(Xb, nacb, rowsq, 1, o_frm, o_att, natt, asums_o);
  k_pred_p2<<<dim3(16, 2, 8), 256, 0, stream>>>(Xb, natt, asums_o, partF);
  k_feat_finish<<<2816, 256, 0, stream>>>(partF, feats);
  k_pred_final<<<16, 256, 0, stream>>>(feats, nacf, o_ca, o_cw);
  // m-phase (on refined)
  k_pred_p1<<<375, 256, 0, stream>>>(Rb, nacb, invr, 0, m_frm, m_att, natt, asums_m);
  k_pred_p2<<<dim3(16, 2, 8), 256, 0, stream>>>(Rb, natt, asums_m, partF);
  k_feat_finish<<<2816, 256, 0, stream>>>(partF, feats);
  k_pred_final<<<16, 256, 0, stream>>>(feats, nacf, m_ca, m_cw);
}

// Round 10
// 837.066 us; speedup vs baseline: 1.0895x; 1.0128x over previous
//
#include <hip/hip_runtime.h>

#define NB 16
#define TT 750
#define DD 2048
#define KK 8
#define CC 21
#define NT 12000

// mu-accumulate t-chunking: 32 chunks of 24 rows (32*24 = 768 >= 750) -> 512 blocks
#define MU_CH 32
#define MU_TCH 24
// pred pass2 t-chunking: 16 chunks of 47 rows (16*47 = 752 >= 750) -> 512 blocks
#define PF_CH 16
#define PF_TCH 47

typedef __bf16 bf16;
typedef __attribute__((ext_vector_type(4))) float floatx4;
typedef __attribute__((ext_vector_type(8))) __bf16 bf16x8;
typedef __attribute__((ext_vector_type(4))) __bf16 bf16x4;

__device__ __forceinline__ float wave_allreduce_sum(float v) {
#pragma unroll
  for (int m = 32; m > 0; m >>= 1) v += __shfl_xor(v, m, 64);
  return v;
}

__device__ __forceinline__ void async_lds16(const bf16* g, bf16* l) {
  __builtin_amdgcn_global_load_lds(
      (const __attribute__((address_space(1))) void*)(g),
      (__attribute__((address_space(3))) void*)(l), 16, 0, 0);
}

// ============ fused prep: W transpose+bf16 | ac_norm | mu_norm0 | x->bf16 =======
__global__ __launch_bounds__(256) void k_prep(
    const float* __restrict__ W, bf16* __restrict__ Wt,
    const float* __restrict__ ac, const float* __restrict__ fg,
    float* __restrict__ nacf, bf16* __restrict__ nacb,
    const float* __restrict__ mup, float* __restrict__ nmu, bf16* __restrict__ nmub,
    const float* __restrict__ x, bf16* __restrict__ Ab) {
  int b = blockIdx.x, tid = threadIdx.x;
  __shared__ float tile[32][33];
  __shared__ float sb[4];
  if (b < 4096) {
    int j0 = (b & 63) * 32, k0 = (b >> 6) * 32;
    int tx = tid & 31, ty = tid >> 5;
#pragma unroll
    for (int i = 0; i < 4; i++)
      tile[ty + 8 * i][tx] = W[(size_t)(k0 + ty + 8 * i) * DD + j0 + tx];
    __syncthreads();
#pragma unroll
    for (int i = 0; i < 4; i++)
      Wt[(size_t)(j0 + ty + 8 * i) * DD + k0 + tx] = (bf16)tile[tx][ty + 8 * i];
    return;
  }
  if (b < 4128) {
    int r = b - 4096;
    int d0 = tid * 8;
    if (r >= 22) {
#pragma unroll
      for (int j = 0; j < 8; j++) nacb[(size_t)r * DD + d0 + j] = (bf16)0.f;
      return;
    }
    const float* src = (r < 21) ? (ac + (size_t)r * DD) : fg;
    float v[8];
    floatx4 a = *(const floatx4*)(src + d0);
    floatx4 c = *(const floatx4*)(src + d0 + 4);
    v[0]=a.x; v[1]=a.y; v[2]=a.z; v[3]=a.w; v[4]=c.x; v[5]=c.y; v[6]=c.z; v[7]=c.w;
    float ss = 0.f;
#pragma unroll
    for (int j = 0; j < 8; j++) ss += v[j] * v[j];
    ss = wave_allreduce_sum(ss);
    int lane = tid & 63, wid = tid >> 6;
    if (lane == 0) sb[wid] = ss;
    __syncthreads();
    float inv = 1.f / (sqrtf(sb[0] + sb[1] + sb[2] + sb[3]) + 1e-9f);
#pragma unroll
    for (int j = 0; j < 8; j++) {
      float nv = v[j] * inv;
      nacf[(size_t)r * DD + d0 + j] = nv;
      nacb[(size_t)r * DD + d0 + j] = (bf16)nv;
    }
    return;
  }
  if (b < 4256) {
    int bb = b - 4128;  // n*8+k
    int n = bb >> 3, k = bb & 7;
    int lane = tid & 63, wid = tid >> 6;
    const float* p = mup + (size_t)k * DD + tid * 8;
    float v[8];
    floatx4 a = *(const floatx4*)p;
    floatx4 c = *(const floatx4*)(p + 4);
    v[0]=a.x; v[1]=a.y; v[2]=a.z; v[3]=a.w; v[4]=c.x; v[5]=c.y; v[6]=c.z; v[7]=c.w;
    float ss = 0.f;
#pragma unroll
    for (int j = 0; j < 8; j++) ss += v[j] * v[j];
    ss = wave_allreduce_sum(ss);
    if (lane == 0) sb[wid] = ss;
    __syncthreads();
    float inv = 1.f / (sqrtf(sb[0] + sb[1] + sb[2] + sb[3]) + 1e-9f);
    float* q = nmu + (size_t)bb * DD + tid * 8;
    bf16* qb = nmub + (size_t)(n * 16 + k) * DD + tid * 8;
#pragma unroll
    for (int j = 0; j < 8; j++) {
      float nv = v[j] * inv;
      q[j] = nv;
      qb[j] = (bf16)nv;
    }
    return;
  }
  int unit0 = (b - 4256) * 4;
#pragma unroll
  for (int u = 0; u < 4; u++) {
    size_t base = ((size_t)(unit0 + u) * 256 + tid) * 8;
    int row = (int)(base >> 11);
    bf16x8 o = {};
    if (row < NT) {
      floatx4 a = *(const floatx4*)(x + base);
      floatx4 c = *(const floatx4*)(x + base + 4);
      o[0]=(bf16)a.x; o[1]=(bf16)a.y; o[2]=(bf16)a.z; o[3]=(bf16)a.w;
      o[4]=(bf16)c.x; o[5]=(bf16)c.y; o[6]=(bf16)c.z; o[7]=(bf16)c.w;
    }
    *(bf16x8*)(Ab + base) = o;
  }
}

// ============ embedding GEMM (round-5 structure + XCD m-band swizzle) ===========
__global__ __launch_bounds__(256) void k_gemm(
    const bf16* __restrict__ Ab, const bf16* __restrict__ Bt,
    const float* __restrict__ bias,
    float* __restrict__ Cout, bf16* __restrict__ Cb, float* __restrict__ rowsq) {
  __shared__ bf16 As[128 * 64];
  __shared__ bf16 Bs[128 * 64];
  int tid = threadIdx.x;
  int bid = blockIdx.x;
  int wid2 = (bid & 7) * 188 + (bid >> 3);  // XCD x owns wid2 in [188x, 188(x+1))
  int mt = wid2 >> 4, nt = wid2 & 15;
  int m0 = mt * 128, n0 = nt * 128;
  int wid = tid >> 6, lane = tid & 63;
  int wm = (wid >> 1) * 64, wn = (wid & 1) * 64;
  int lrow = lane & 15, lko = (lane >> 4) * 8;
  int lr7 = lrow & 7;
  floatx4 acc[4][4] = {};
  int crow = tid >> 3;
  int jg = ((tid & 7) ^ (crow & 7)) * 8;
  const bf16* gA = Ab + (size_t)(m0 + crow) * DD + jg;
  const bf16* gB = Bt + (size_t)(n0 + crow) * DD + jg;
  bf16* lA = As + tid * 8;
  bf16* lB = Bs + tid * 8;
  for (int k0 = 0; k0 < DD; k0 += 64) {
#pragma unroll
    for (int s = 0; s < 4; s++)
      async_lds16(gA + (size_t)(32 * s) * DD + k0, lA + 2048 * s);
#pragma unroll
    for (int s = 0; s < 4; s++)
      async_lds16(gB + (size_t)(32 * s) * DD + k0, lB + 2048 * s);
    __syncthreads();
#pragma unroll
    for (int ks = 0; ks < 64; ks += 32) {
      bf16x8 af[4], bfr[4];
#pragma unroll
      for (int i = 0; i < 4; i++) {
        int sw = (((ks + lko) >> 3) ^ lr7) * 8;
        af[i] = *(const bf16x8*)(As + (wm + i * 16 + lrow) * 64 + sw);
      }
#pragma unroll
      for (int jj = 0; jj < 4; jj++) {
        int sw = (((ks + lko) >> 3) ^ lr7) * 8;
        bfr[jj] = *(const bf16x8*)(Bs + (wn + jj * 16 + lrow) * 64 + sw);
      }
#pragma unroll
      for (int i = 0; i < 4; i++)
#pragma unroll
        for (int jj = 0; jj < 4; jj++)
          acc[i][jj] = __builtin_amdgcn_mfma_f32_16x16x32_bf16(af[i], bfr[jj], acc[i][jj], 0, 0, 0);
    }
    __syncthreads();
  }
  int quad = lane >> 4;
  float bv[4];
#pragma unroll
  for (int jj = 0; jj < 4; jj++) bv[jj] = bias[n0 + wn + jj * 16 + lrow];
#pragma unroll
  for (int i = 0; i < 4; i++) {
#pragma unroll
    for (int r = 0; r < 4; r++) {
      int row = m0 + wm + i * 16 + quad * 4 + r;
      bool ok = (row < NT);
      float sq = 0.f;
#pragma unroll
      for (int jj = 0; jj < 4; jj++) {
        int col = n0 + wn + jj * 16 + lrow;
        float v = acc[i][jj][r] + bv[jj];
        v = fmaxf(v, 0.f);
        if (ok) {
          Cout[(size_t)row * DD + col] = v;
          Cb[(size_t)row * DD + col] = (bf16)v;
        }
        sq += v * v;
      }
#pragma unroll
      for (int m = 1; m < 16; m <<= 1) sq += __shfl_xor(sq, m, 64);
      if (ok && lrow == 0) atomicAdd(&rowsq[row], sq);
    }
  }
}

// ============ EM score pass: MFMA [64t x 16k], BK=256 deep-pipelined staging =====
__global__ __launch_bounds__(256) void k_score(
    const bf16* __restrict__ Xb, const bf16* __restrict__ nmub,
    const float* __restrict__ rowsq,
    float* __restrict__ z, float* __restrict__ rowsum) {
  __shared__ bf16 As[2][64 * 256];
  __shared__ bf16 Bs[2][16 * 256];
  int tid = threadIdx.x, lane = tid & 63, w = tid >> 6;
  int m0 = blockIdx.x * 64, n = blockIdx.y;
  int lrow = lane & 15, lko = (lane >> 4) * 8, lr7 = lrow & 7;
  int scg = tid & 31;
  int srow = tid >> 5;
  const bf16* gXn = Xb + (size_t)(n * TT + m0) * DD;
  const bf16* gBn = nmub + (size_t)(n * 16) * DD;
#pragma unroll
  for (int r = 0; r < 8; r++) {
    int row = r * 8 + srow;
    int cgg = (scg & 24) | ((scg & 7) ^ (row & 7));
    async_lds16(gXn + (size_t)row * DD + cgg * 8, &As[0][r * 2048 + tid * 8]);
  }
#pragma unroll
  for (int r = 0; r < 2; r++) {
    int row = r * 8 + srow;
    int cgg = (scg & 24) | ((scg & 7) ^ (row & 7));
    async_lds16(gBn + (size_t)row * DD + cgg * 8, &Bs[0][r * 2048 + tid * 8]);
  }
  floatx4 acc = {};
  int buf = 0;
  for (int k0 = 0; k0 < DD; k0 += 256) {
    __syncthreads();
    if (k0 + 256 < DD) {
#pragma unroll
      for (int r = 0; r < 8; r++) {
        int row = r * 8 + srow;
        int cgg = (scg & 24) | ((scg & 7) ^ (row & 7));
        async_lds16(gXn + (size_t)row * DD + k0 + 256 + cgg * 8,
                    &As[buf ^ 1][r * 2048 + tid * 8]);
      }
#pragma unroll
      for (int r = 0; r < 2; r++) {
        int row = r * 8 + srow;
        int cgg = (scg & 24) | ((scg & 7) ^ (row & 7));
        async_lds16(gBn + (size_t)row * DD + k0 + 256 + cgg * 8,
                    &Bs[buf ^ 1][r * 2048 + tid * 8]);
      }
    }
    int arow = w * 16 + lrow;
#pragma unroll
    for (int ks = 0; ks < 256; ks += 32) {
      int cg = (ks + lko) >> 3;
      int cgl = (cg & 24) | ((cg & 7) ^ lr7);
      bf16x8 a = *(const bf16x8*)(&As[buf][arow * 256 + cgl * 8]);
      bf16x8 b = *(const bf16x8*)(&Bs[buf][lrow * 256 + cgl * 8]);
      acc = __builtin_amdgcn_mfma_f32_16x16x32_bf16(a, b, acc, 0, 0, 0);
    }
    buf ^= 1;
  }
  int quad = lane >> 4;
  int k = lrow;
  float pacc = 0.f;
#pragma unroll
  for (int r = 0; r < 4; r++) {
    int trow = m0 + w * 16 + quad * 4 + r;
    bool valid = (trow < TT);
    float rq = valid ? rowsq[n * TT + trow] : 1.f;
    float s = acc[r] * (5.f / (sqrtf(rq) + 1e-9f));
    float mx = s;
    mx = fmaxf(mx, __shfl_xor(mx, 1, 64));
    mx = fmaxf(mx, __shfl_xor(mx, 2, 64));
    mx = fmaxf(mx, __shfl_xor(mx, 4, 64));
    float e = __expf(s - mx);
    float se = e;
    se += __shfl_xor(se, 1, 64);
    se += __shfl_xor(se, 2, 64);
    se += __shfl_xor(se, 4, 64);
    float zz = e / se;
    zz = (valid && k < 8) ? zz : 0.f;
    if (valid && k < 8) z[(size_t)(n * TT + trow) * 8 + k] = zz;
    pacc += zz;
  }
  pacc += __shfl_xor(pacc, 16, 64);
  pacc += __shfl_xor(pacc, 32, 64);
  if (lane < 8) atomicAdd(&rowsum[n * 8 + lane], pacc);
}

// ============ EM accumulate: mu_part = z @ X (32 chunks, 2 blocks/CU) ===========
__global__ __launch_bounds__(256) void k_mu_accum(
    const bf16* __restrict__ Xb, const float* __restrict__ z,
    float* __restrict__ part2) {
  int n = blockIdx.x, tc = blockIdx.y, tid = threadIdx.x;
  int t0 = tc * MU_TCH;
  int tcnt = min(MU_TCH, TT - t0);
  __shared__ float zs[MU_TCH * 8];
  for (int i = tid; i < tcnt * 8; i += 256) zs[i] = z[(size_t)(n * TT + t0) * 8 + i];
  __syncthreads();
  float acc[8][8] = {};
  const bf16* xp = Xb + (size_t)(n * TT + t0) * DD + tid * 8;
  bf16x8 x0 = *(const bf16x8*)xp;
  bf16x8 x1 = (tcnt > 1) ? *(const bf16x8*)(xp + DD) : x0;
  for (int tt = 0; tt < tcnt; tt++) {
    bf16x8 cur = x0;
    x0 = x1;
    if (tt + 2 < tcnt) x1 = *(const bf16x8*)(xp + (size_t)(tt + 2) * DD);
    float xv[8];
#pragma unroll
    for (int j = 0; j < 8; j++) xv[j] = (float)cur[j];
    floatx4 za = *(const floatx4*)&zs[tt * 8];
    floatx4 zb4 = *(const floatx4*)&zs[tt * 8 + 4];
    float zk[8] = {za.x, za.y, za.z, za.w, zb4.x, zb4.y, zb4.z, zb4.w};
#pragma unroll
    for (int k = 0; k < 8; k++)
#pragma unroll
      for (int j = 0; j < 8; j++) acc[k][j] += zk[k] * xv[j];
  }
  float* pb = part2 + ((size_t)(tc * 16 + n) * 8) * DD + tid * 8;
#pragma unroll
  for (int k = 0; k < 8; k++) {
    floatx4 lo = {acc[k][0], acc[k][1], acc[k][2], acc[k][3]};
    floatx4 hi = {acc[k][4], acc[k][5], acc[k][6], acc[k][7]};
    *(floatx4*)(pb + (size_t)k * DD) = lo;
    *(floatx4*)(pb + (size_t)k * DD + 4) = hi;
  }
}

// ============ EM finish =========================================================
__global__ void k_mu_finish(const float* __restrict__ part2, const float* __restrict__ rs,
                            float* __restrict__ accS_raw, float* __restrict__ mu_ws,
                            float* __restrict__ mu_out, float* __restrict__ nmu_out,
                            bf16* __restrict__ nmub) {
  int b = blockIdx.x;  // n*8+k
  int n = b >> 3, k = b & 7;
  int tid = threadIdx.x, lane = tid & 63, wid = tid >> 6;
  int d0 = tid * 8;
  float s[8] = {};
#pragma unroll 4
  for (int c = 0; c < MU_CH; c++) {
    const float* p = part2 + ((size_t)(c * 16 + n) * 8 + k) * DD + d0;
    floatx4 a = *(const floatx4*)p;
    floatx4 cc = *(const floatx4*)(p + 4);
    s[0] += a.x; s[1] += a.y; s[2] += a.z; s[3] += a.w;
    s[4] += cc.x; s[5] += cc.y; s[6] += cc.z; s[7] += cc.w;
  }
  if (accS_raw != nullptr) {
#pragma unroll
    for (int j = 0; j < 8; j++) accS_raw[(size_t)b * DD + d0 + j] = s[j];
    return;
  }
  float invr = 1.f / (rs[b] + 1e-9f);
  float m[8];
#pragma unroll
  for (int j = 0; j < 8; j++) m[j] = s[j] * invr;
#pragma unroll
  for (int j = 0; j < 8; j++) mu_ws[(size_t)b * DD + d0 + j] = m[j];
  if (mu_out != nullptr) {
#pragma unroll
    for (int j = 0; j < 8; j++) mu_out[(size_t)b * DD + d0 + j] = m[j];
  }
  float ss = 0.f;
#pragma unroll
  for (int j = 0; j < 8; j++) ss += m[j] * m[j];
  ss = wave_allreduce_sum(ss);
  __shared__ float sb[4];
  if (lane == 0) sb[wid] = ss;
  __syncthreads();
  float inv = 1.f / (sqrtf(sb[0] + sb[1] + sb[2] + sb[3]) + 1e-9f);
  bf16* qb = nmub + (size_t)(n * 16 + k) * DD + d0;
#pragma unroll
  for (int j = 0; j < 8; j++) {
    float nv = m[j] * inv;
    nmu_out[(size_t)b * DD + d0 + j] = nv;
    qb[j] = (bf16)nv;
  }
}

// ============ Woodbury + mu_pred ================================================
__global__ void k_wood_mupred(const float* __restrict__ z, const float* __restrict__ rowsum,
                              const float* __restrict__ S, const float* __restrict__ mu,
                              float* __restrict__ G,
                              const float* __restrict__ nmu, const float* __restrict__ nacf,
                              float* __restrict__ mupred) {
  int tid = threadIdx.x;
  if (blockIdx.x >= 16) {
    int b = blockIdx.x - 16;
    int lane = tid & 63, wid = tid >> 6;
    const float* v = nmu + (size_t)b * DD;
    __shared__ float scr[21];
    for (int c = wid; c < 21; c += 4) {
      const float* a = nacf + (size_t)c * DD;
      float s = 0.f;
      for (int i = lane * 4; i < DD; i += 256) {
        floatx4 vv = *(const floatx4*)(v + i);
        floatx4 aa = *(const floatx4*)(a + i);
        s += vv.x * aa.x + vv.y * aa.y + vv.z * aa.z + vv.w * aa.w;
      }
      s = wave_allreduce_sum(s);
      if (lane == 0) scr[c] = s * 20.f;
    }
    __syncthreads();
    if (tid == 0) {
      float mx = scr[0];
      for (int c = 1; c < 21; c++) mx = fmaxf(mx, scr[c]);
      float se = 0.f;
      for (int c = 0; c < 21; c++) se += __expf(scr[c] - mx);
      float inv = 1.f / se;
      for (int c = 0; c < 21; c++) mupred[(size_t)b * 21 + c] = __expf(scr[c] - mx) * inv;
    }
    return;
  }
  int n = blockIdx.x;
  __shared__ float VU[8][8];
  __shared__ float Mi[8][8];
  __shared__ float invrs[8];
  __shared__ float vus[64][4];
  if (tid < 8) invrs[tid] = 1.f / (rowsum[n * 8 + tid] + 1e-9f);
  {
    int pr = tid >> 2, sl = tid & 3;
    int jj = pr >> 3, kk = pr & 7;
    float s = 0.f;
    for (int t = sl; t < TT; t += 4) {
      const float* zp = z + (size_t)(n * TT + t) * 8;
      s += zp[jj] * zp[kk];
    }
    vus[pr][sl] = s;
  }
  __syncthreads();
  if (tid < 64)
    VU[tid >> 3][tid & 7] =
        (vus[tid][0] + vus[tid][1] + vus[tid][2] + vus[tid][3]) * invrs[tid >> 3];
  __syncthreads();
  if (tid == 0) {
    float M[8][16];
    for (int i = 0; i < 8; i++)
      for (int jj = 0; jj < 8; jj++) {
        M[i][jj] = ((i == jj) ? 1.f : 0.f) - 0.25f * VU[i][jj];
        M[i][8 + jj] = (i == jj) ? 1.f : 0.f;
      }
    for (int c = 0; c < 8; c++) {
      float pv = 1.f / M[c][c];
      for (int jj = 0; jj < 16; jj++) M[c][jj] *= pv;
      for (int rr = 0; rr < 8; rr++)
        if (rr != c) {
          float f = M[rr][c];
          for (int jj = 0; jj < 16; jj++) M[rr][jj] -= f * M[c][jj];
        }
    }
    for (int i = 0; i < 8; i++)
      for (int jj = 0; jj < 8; jj++) Mi[i][jj] = M[i][8 + jj];
  }
  __syncthreads();
  const float* mun = mu + (size_t)n * 8 * DD;
  const float* Sn = S + (size_t)n * 8 * DD;
  float* Gn = G + (size_t)n * 8 * DD;
  for (int d = tid; d < DD; d += 256) {
    float m[8], P[8];
#pragma unroll
    for (int k = 0; k < 8; k++) m[k] = mun[k * DD + d];
#pragma unroll
    for (int k = 0; k < 8; k++) {
      float s = 0.f;
#pragma unroll
      for (int jj = 0; jj < 8; jj++) s += VU[k][jj] * m[jj];
      P[k] = 0.5f * s + Sn[k * DD + d] * invrs[k];
    }
#pragma unroll
    for (int jj = 0; jj < 8; jj++) {
      float s = 0.f;
#pragma unroll
      for (int k = 0; k < 8; k++) s += Mi[jj][k] * P[k];
      Gn[jj * DD + d] = 0.5f * (0.5f * m[jj] + 0.25f * s);
    }
  }
}

// ============ RW pass ===========================================================
__global__ __launch_bounds__(256) void k_rw_passC(
    const bf16* __restrict__ Xb, const float* __restrict__ z,
    const float* __restrict__ G, bf16* __restrict__ refb,
    float* __restrict__ invr) {
  int n = blockIdx.x, ch = blockIdx.y, tid = threadIdx.x;
  int lane = tid & 63, wid = tid >> 6;
  int d0 = tid * 8;
  int t0 = ch * 30;
  const float* Gn = G + (size_t)n * 8 * DD;
  float gr[8][8];
#pragma unroll
  for (int k = 0; k < 8; k++) {
    floatx4 a = *(const floatx4*)(Gn + k * DD + d0);
    floatx4 b = *(const floatx4*)(Gn + k * DD + d0 + 4);
    gr[k][0]=a.x; gr[k][1]=a.y; gr[k][2]=a.z; gr[k][3]=a.w;
    gr[k][4]=b.x; gr[k][5]=b.y; gr[k][6]=b.z; gr[k][7]=b.w;
  }
  __shared__ float red[30][4];
  const bf16* xrow = Xb + (size_t)n * TT * DD;
  bf16x8 xg = *(const bf16x8*)(xrow + (size_t)t0 * DD + d0);
  for (int tt = 0; tt < 30; tt++) {
    int t = t0 + tt;
    bf16x8 x8 = xg;
    if (tt + 1 < 30) xg = *(const bf16x8*)(xrow + (size_t)(t + 1) * DD + d0);
    const float* zp = z + (size_t)(n * TT + t) * 8;
    floatx4 za = *(const floatx4*)zp;
    floatx4 zb4 = *(const floatx4*)(zp + 4);
    float zt[8] = {za.x, za.y, za.z, za.w, zb4.x, zb4.y, zb4.z, zb4.w};
    float r[8];
#pragma unroll
    for (int j = 0; j < 8; j++) {
      float s = 0.5f * (float)x8[j];
#pragma unroll
      for (int k = 0; k < 8; k++) s += zt[k] * gr[k][j];
      r[j] = s;
    }
    bf16x8 ro;
#pragma unroll
    for (int j = 0; j < 8; j++) ro[j] = (bf16)r[j];
    *(bf16x8*)(refb + (size_t)(n * TT + t) * DD + d0) = ro;
    float ss = 0.f;
#pragma unroll
    for (int j = 0; j < 8; j++) ss += r[j] * r[j];
    ss = wave_allreduce_sum(ss);
    if (lane == 0) red[tt][wid] = ss;
  }
  __syncthreads();
  if (tid < 30) {
    float tot = red[tid][0] + red[tid][1] + red[tid][2] + red[tid][3];
    invr[n * TT + t0 + tid] = 1.f / (sqrtf(tot) + 1e-9f);
  }
}

// ============ pred pass1 (BK=256 deep-pipelined staging) ========================
__global__ __launch_bounds__(256) void k_pred_p1(
    const bf16* __restrict__ Xb, const bf16* __restrict__ nacb,
    const float* __restrict__ invn, int mode,
    float* __restrict__ out_frm, float* __restrict__ out_att,
    float* __restrict__ natt, float* __restrict__ att_sums) {
  __shared__ bf16 As[2][32 * 256];
  __shared__ bf16 Bs[2][32 * 256];
  __shared__ float ssum[2][32];
  int tid = threadIdx.x, lane = tid & 63, wid = tid >> 6;
  int m0 = blockIdx.x * 32;
  if (tid < 64) ssum[tid >> 5][tid & 31] = 0.f;
  int lrow = lane & 15, lko = (lane >> 4) * 8, lr7 = lrow & 7;
  int r0 = (wid & 1) * 16, c0 = (wid >> 1) * 16;
  int scg = tid & 31;
  int srow = tid >> 5;
  const bf16* gA = Xb + (size_t)m0 * DD;
  const bf16* gB = nacb;
#pragma unroll
  for (int r = 0; r < 4; r++) {
    int row = r * 8 + srow;
    int cgg = (scg & 24) | ((scg & 7) ^ (row & 7));
    async_lds16(gA + (size_t)row * DD + cgg * 8, &As[0][r * 2048 + tid * 8]);
    async_lds16(gB + (size_t)row * DD + cgg * 8, &Bs[0][r * 2048 + tid * 8]);
  }
  floatx4 acc = {};
  int buf = 0;
  for (int k0 = 0; k0 < DD; k0 += 256) {
    __syncthreads();
    if (k0 + 256 < DD) {
#pragma unroll
      for (int r = 0; r < 4; r++) {
        int row = r * 8 + srow;
        int cgg = (scg & 24) | ((scg & 7) ^ (row & 7));
        async_lds16(gA + (size_t)row * DD + k0 + 256 + cgg * 8,
                    &As[buf ^ 1][r * 2048 + tid * 8]);
        async_lds16(gB + (size_t)row * DD + k0 + 256 + cgg * 8,
                    &Bs[buf ^ 1][r * 2048 + tid * 8]);
      }
    }
#pragma unroll
    for (int ks = 0; ks < 256; ks += 32) {
      int cg = (ks + lko) >> 3;
      int cgl = (cg & 24) | ((cg & 7) ^ lr7);
      bf16x8 a = *(const bf16x8*)(&As[buf][(r0 + lrow) * 256 + cgl * 8]);
      bf16x8 b = *(const bf16x8*)(&Bs[buf][(c0 + lrow) * 256 + cgl * 8]);
      acc = __builtin_amdgcn_mfma_f32_16x16x32_bf16(a, b, acc, 0, 0, 0);
    }
    buf ^= 1;
  }
  __syncthreads();
  int quad = lane >> 4;
  int nbase = m0 / TT;
  int c = c0 + lrow;
#pragma unroll
  for (int r = 0; r < 4; r++) {
    int row = m0 + r0 + quad * 4 + r;
    if (c < 22) {
      float iv = mode ? (1.f / (sqrtf(invn[row]) + 1e-9f)) : invn[row];
      float s = acc[r] * iv * 20.f;
      float sg = 1.f / (1.f + __expf(-s));
      int n_loc = row / TT - nbase;
      if (c < 21) out_frm[(size_t)row * 21 + c] = s;
      else out_att[row] = sg;
      natt[(size_t)row * 22 + c] = sg;
      atomicAdd(&ssum[n_loc][c], sg);
    }
  }
  __syncthreads();
  if (tid < 64) {
    int nl = tid >> 5, cs = tid & 31;
    int nn = nbase + nl;
    if (cs < 22 && nn < NB) {
      float v = ssum[nl][cs];
      if (v != 0.f) atomicAdd(&att_sums[nn * 22 + cs], v);
    }
  }
}

// ============ pred pass2 (16 t-chunks of 47, 2 blocks/CU) =======================
__global__ __launch_bounds__(256) void k_pred_p2(
    const bf16* __restrict__ Xb, const float* __restrict__ natt,
    const float* __restrict__ sums, float* __restrict__ partF) {
  int n = blockIdx.x, dh = blockIdx.y, tc = blockIdx.z, tid = threadIdx.x;
  int d = dh * 1024 + tid * 4;
  int t0 = tc * PF_TCH;
  int tcnt = min(PF_TCH, TT - t0);
  __shared__ float sw[PF_TCH * 22];
  for (int i = tid; i < tcnt * 22; i += 256) {
    int c = i - (i / 22) * 22;
    sw[i] = natt[(size_t)(n * TT + t0) * 22 + i] / (sums[n * 22 + c] + 1e-5f);
  }
  __syncthreads();
  float ac[22][4] = {};
  const bf16* xrow = Xb + (size_t)n * TT * DD;
  bf16x4 xg = *(const bf16x4*)(xrow + (size_t)t0 * DD + d);
  for (int tt = 0; tt < tcnt; tt++) {
    bf16x4 x4 = xg;
    if (tt + 1 < tcnt) xg = *(const bf16x4*)(xrow + (size_t)(t0 + tt + 1) * DD + d);
    float xv[4] = {(float)x4[0], (float)x4[1], (float)x4[2], (float)x4[3]};
#pragma unroll
    for (int cidx = 0; cidx < 22; cidx++) {
      float w = sw[tt * 22 + cidx];
#pragma unroll
      for (int jj = 0; jj < 4; jj++) ac[cidx][jj] += w * xv[jj];
    }
  }
  float* pb = partF + ((size_t)(n * PF_CH + tc) * 22) * DD + d;
#pragma unroll
  for (int cidx = 0; cidx < 22; cidx++) {
    floatx4 v = {ac[cidx][0], ac[cidx][1], ac[cidx][2], ac[cidx][3]};
    *(floatx4*)(pb + (size_t)cidx * DD) = v;
  }
}

// ============ reduce feats partials (full-BW grid) ==============================
__global__ void k_feat_finish(const float* __restrict__ partF, float* __restrict__ feats) {
  int idx = blockIdx.x * 256 + threadIdx.x;
  if (idx >= NB * 22 * DD) return;
  int n = idx / (22 * DD);
  int rem = idx - n * (22 * DD);
  const float* p = partF + ((size_t)n * PF_CH) * (22 * DD) + rem;
  float s = 0.f;
#pragma unroll
  for (int tc = 0; tc < PF_CH; tc++) s += p[(size_t)tc * 22 * DD];
  feats[idx] = s;
}

// ============ final scores + softmax ============================================
__global__ void k_pred_final(const float* __restrict__ feats, const float* __restrict__ nacf,
                             float* __restrict__ oca, float* __restrict__ ocw) {
  int n = blockIdx.x, tid = threadIdx.x, lane = tid & 63, wid = tid >> 6;
  const float* fn = feats + (size_t)n * 22 * DD;
  __shared__ float rnorm[22];
  __shared__ float scr[42];
  for (int r = wid; r < 22; r += 4) {
    const float* fv = fn + (size_t)r * DD;
    float s = 0.f;
    for (int i = lane * 4; i < DD; i += 256) {
      floatx4 v = *(const floatx4*)(fv + i);
      s += v.x * v.x + v.y * v.y + v.z * v.z + v.w * v.w;
    }
    s = wave_allreduce_sum(s);
    if (lane == 0) rnorm[r] = 1.f / (sqrtf(s) + 1e-9f);
  }
  __syncthreads();
  for (int idx = wid; idx < 42; idx += 4) {
    int c = (idx < 21) ? idx : (idx - 21);
    int fr = (idx < 21) ? c : 21;
    const float* fv = fn + (size_t)fr * DD;
    const float* av = nacf + (size_t)c * DD;
    float s = 0.f;
    for (int i = lane * 4; i < DD; i += 256) {
      floatx4 v = *(const floatx4*)(fv + i);
      floatx4 a = *(const floatx4*)(av + i);
      s += v.x * a.x + v.y * a.y + v.z * a.z + v.w * a.w;
    }
    s = wave_allreduce_sum(s);
    if (lane == 0) scr[idx] = s * 20.f * rnorm[fr];
  }
  __syncthreads();
  if (tid < 2) {
    int base = (tid == 0) ? 21 : 0;
    float* dst = ((tid == 0) ? oca : ocw) + (size_t)n * 21;
    float mx = scr[base];
    for (int c = 1; c < 21; c++) mx = fmaxf(mx, scr[base + c]);
    float se = 0.f;
    for (int c = 0; c < 21; c++) se += __expf(scr[base + c] - mx);
    float inv = 1.f / se;
    for (int c = 0; c < 21; c++) dst[c] = __expf(scr[base + c] - mx) * inv;
  }
}

extern "C" void kernel_launch(void* const* d_in, const int* in_sizes, int n_in,
                              void* d_out, int out_size, void* d_ws, size_t ws_size,
                              hipStream_t stream) {
  const float* x_in = (const float*)d_in[0];
  const float* W = (const float*)d_in[1];
  const float* bemb = (const float*)d_in[2];
  const float* mup = (const float*)d_in[3];
  const float* ac = (const float*)d_in[4];
  const float* fg = (const float*)d_in[5];
  float* out = (float*)d_out;

  char* ws = (char*)d_ws;
  bf16* Wt = (bf16*)ws;                       // 8,388,608
  bf16* Xb = (bf16*)(ws + 8388608);           // 49,283,072 (12032 rows)
  bf16* Rb = (bf16*)(ws + 57671680);          // 49,283,072
  bf16* Ab = (bf16*)(ws + 106954752);         // 49,283,072 (alias: part2 / partF)
  float* part2 = (float*)(ws + 106954752);    // 33.5 MB (EM phase, 32 chunks)
  float* partF = (float*)(ws + 106954752);    // 46.1 MB (pred phase, 16 chunks)
  bf16* nacb = (bf16*)(ws + 156237824);       // 131,072
  float* f = (float*)(ws + 156368896);
  float* nacf = f;                       // 45,056
  float* mu = nacf + 45056;              // 262,144
  float* nmu = mu + 262144;              // 262,144
  bf16* nmub = (bf16*)(nmu + 262144);    // 262,144 floats worth (1 MB)
  float* accS = nmu + 262144 + 262144;   // 262,144
  float* G = accS + 262144;              // 262,144
  float* z = G + 262144;                 // 96,000  [n][750][8]
  float* natt = z + 96000;               // 264,000
  float* feats = natt + 264000;          // 720,896
  float* invr = feats + 720896;          // 12,032
  float* rowsum = invr + 12032;          // 768 (zeroed)
  float* asums_o = rowsum + 768;         // 352 (zeroed)
  float* asums_m = asums_o + 352;        // 352 (zeroed)
  float* rowsq = asums_m + 352;          // 12,032 (zeroed)

  float* o_ca = out;
  float* o_cw = out + 336;
  float* o_att = out + 672;
  float* o_frm = out + 12672;
  float* m_ca = out + 264672;
  float* m_cw = out + 265008;
  float* m_att = out + 265344;
  float* m_frm = out + 277344;
  float* x_out = out + 529344;
  float* mu_out = out + 25105344;
  float* mup_out = out + 25367488;

  hipMemsetAsync(rowsum, 0, (768 + 352 + 352 + 12032) * sizeof(float), stream);
  hipMemsetAsync(nmub, 0, (size_t)NB * 16 * DD * sizeof(bf16), stream);
  k_prep<<<7264, 256, 0, stream>>>(W, Wt, ac, fg, nacf, nacb, mup, nmu, nmub, x_in, Ab);
  k_gemm<<<1504, 256, 0, stream>>>(Ab, Wt, bemb, x_out, Xb, rowsq);
  for (int it = 0; it < 5; it++) {
    bool last = (it == 4);
    k_score<<<dim3(12, 16), 256, 0, stream>>>(Xb, nmub, rowsq, z, rowsum + it * 128);
    k_mu_accum<<<dim3(16, MU_CH), 256, 0, stream>>>(Xb, z, part2);
    k_mu_finish<<<128, 256, 0, stream>>>(part2, rowsum + it * 128, nullptr, mu,
                                         last ? mu_out : nullptr, nmu, nmub);
  }
  k_score<<<dim3(12, 16), 256, 0, stream>>>(Xb, nmub, rowsq, z, rowsum + 5 * 128);
  k_mu_accum<<<dim3(16, MU_CH), 256, 0, stream>>>(Xb, z, part2);
  k_mu_finish<<<128, 256, 0, stream>>>(part2, nullptr, accS, nullptr, nullptr, nullptr, nullptr);
  k_wood_mupred<<<144, 256, 0, stream>>>(z, rowsum + 5 * 128, accS, mu, G, nmu, nacf, mup_out);
  k_rw_passC<<<dim3(16, 25), 256, 0, stream>>>(Xb, z, G, Rb, invr);
  // o-phase (on x)
  k_pred_p1<<<375, 256, 0, stream>>>(Xb, nacb, rowsq, 1, o_frm, o_att, natt, asums_o);
  k_pred_p2<<<dim3(16, 2, PF_CH), 256, 0, stream>>>(Xb, natt, asums_o, partF);
  k_feat_finish<<<2816, 256, 0, stream>>>(partF, feats);
  k_pred_final<<<16, 256, 0, stream>>>(feats, nacf, o_ca, o_cw);
  // m-phase (on refined)
  k_pred_p1<<<375, 256, 0, stream>>>(Rb, nacb, invr, 0, m_frm, m_att, natt, asums_m);
  k_pred_p2<<<dim3(16, 2, PF_CH), 256, 0, stream>>>(Rb, natt, asums_m, partF);
  k_feat_finish<<<2816, 256, 0, stream>>>(partF, feats);
  k_pred_final<<<16, 256, 0, stream>>>(feats, nacf, m_ca, m_cw);
}

// Round 11
// 829.743 us; speedup vs baseline: 1.0991x; 1.0088x over previous
//
#include <hip/hip_runtime.h>

#define NB 16
#define TT 750
#define DD 2048
#define KK 8
#define CC 21
#define NT 12000

// mu-accumulate t-chunking: 32 chunks of 24 rows (32*24 = 768 >= 750) -> 512 blocks
#define MU_CH 32
#define MU_TCH 24
// pred pass2 t-chunking: 16 chunks of 47 rows (16*47 = 752 >= 750) -> 512 blocks
#define PF_CH 16
#define PF_TCH 47

typedef __bf16 bf16;
typedef __attribute__((ext_vector_type(4))) float floatx4;
typedef __attribute__((ext_vector_type(8))) __bf16 bf16x8;
typedef __attribute__((ext_vector_type(4))) __bf16 bf16x4;

__device__ __forceinline__ float wave_allreduce_sum(float v) {
#pragma unroll
  for (int m = 32; m > 0; m >>= 1) v += __shfl_xor(v, m, 64);
  return v;
}

__device__ __forceinline__ void async_lds16(const bf16* g, bf16* l) {
  __builtin_amdgcn_global_load_lds(
      (const __attribute__((address_space(1))) void*)(g),
      (__attribute__((address_space(3))) void*)(l), 16, 0, 0);
}

// ============ fused prep: W transpose+bf16 | ac_norm | mu_norm0 | x->bf16 =======
__global__ __launch_bounds__(256) void k_prep(
    const float* __restrict__ W, bf16* __restrict__ Wt,
    const float* __restrict__ ac, const float* __restrict__ fg,
    float* __restrict__ nacf, bf16* __restrict__ nacb,
    const float* __restrict__ mup, float* __restrict__ nmu, bf16* __restrict__ nmub,
    const float* __restrict__ x, bf16* __restrict__ Ab) {
  int b = blockIdx.x, tid = threadIdx.x;
  __shared__ float tile[32][33];
  __shared__ float sb[4];
  if (b < 4096) {
    int j0 = (b & 63) * 32, k0 = (b >> 6) * 32;
    int tx = tid & 31, ty = tid >> 5;
#pragma unroll
    for (int i = 0; i < 4; i++)
      tile[ty + 8 * i][tx] = W[(size_t)(k0 + ty + 8 * i) * DD + j0 + tx];
    __syncthreads();
#pragma unroll
    for (int i = 0; i < 4; i++)
      Wt[(size_t)(j0 + ty + 8 * i) * DD + k0 + tx] = (bf16)tile[tx][ty + 8 * i];
    return;
  }
  if (b < 4128) {
    int r = b - 4096;
    int d0 = tid * 8;
    if (r >= 22) {
#pragma unroll
      for (int j = 0; j < 8; j++) nacb[(size_t)r * DD + d0 + j] = (bf16)0.f;
      return;
    }
    const float* src = (r < 21) ? (ac + (size_t)r * DD) : fg;
    float v[8];
    floatx4 a = *(const floatx4*)(src + d0);
    floatx4 c = *(const floatx4*)(src + d0 + 4);
    v[0]=a.x; v[1]=a.y; v[2]=a.z; v[3]=a.w; v[4]=c.x; v[5]=c.y; v[6]=c.z; v[7]=c.w;
    float ss = 0.f;
#pragma unroll
    for (int j = 0; j < 8; j++) ss += v[j] * v[j];
    ss = wave_allreduce_sum(ss);
    int lane = tid & 63, wid = tid >> 6;
    if (lane == 0) sb[wid] = ss;
    __syncthreads();
    float inv = 1.f / (sqrtf(sb[0] + sb[1] + sb[2] + sb[3]) + 1e-9f);
#pragma unroll
    for (int j = 0; j < 8; j++) {
      float nv = v[j] * inv;
      nacf[(size_t)r * DD + d0 + j] = nv;
      nacb[(size_t)r * DD + d0 + j] = (bf16)nv;
    }
    return;
  }
  if (b < 4256) {
    int bb = b - 4128;  // n*8+k
    int n = bb >> 3, k = bb & 7;
    int lane = tid & 63, wid = tid >> 6;
    const float* p = mup + (size_t)k * DD + tid * 8;
    float v[8];
    floatx4 a = *(const floatx4*)p;
    floatx4 c = *(const floatx4*)(p + 4);
    v[0]=a.x; v[1]=a.y; v[2]=a.z; v[3]=a.w; v[4]=c.x; v[5]=c.y; v[6]=c.z; v[7]=c.w;
    float ss = 0.f;
#pragma unroll
    for (int j = 0; j < 8; j++) ss += v[j] * v[j];
    ss = wave_allreduce_sum(ss);
    if (lane == 0) sb[wid] = ss;
    __syncthreads();
    float inv = 1.f / (sqrtf(sb[0] + sb[1] + sb[2] + sb[3]) + 1e-9f);
    float* q = nmu + (size_t)bb * DD + tid * 8;
    bf16* qb = nmub + (size_t)(n * 16 + k) * DD + tid * 8;
#pragma unroll
    for (int j = 0; j < 8; j++) {
      float nv = v[j] * inv;
      q[j] = nv;
      qb[j] = (bf16)nv;
    }
    return;
  }
  int unit0 = (b - 4256) * 4;
#pragma unroll
  for (int u = 0; u < 4; u++) {
    size_t base = ((size_t)(unit0 + u) * 256 + tid) * 8;
    int row = (int)(base >> 11);
    bf16x8 o = {};
    if (row < NT) {
      floatx4 a = *(const floatx4*)(x + base);
      floatx4 c = *(const floatx4*)(x + base + 4);
      o[0]=(bf16)a.x; o[1]=(bf16)a.y; o[2]=(bf16)a.z; o[3]=(bf16)a.w;
      o[4]=(bf16)c.x; o[5]=(bf16)c.y; o[6]=(bf16)c.z; o[7]=(bf16)c.w;
    }
    *(bf16x8*)(Ab + base) = o;
  }
}

// ============ embedding GEMM (round-5 structure + XCD m-band swizzle) ===========
__global__ __launch_bounds__(256) void k_gemm(
    const bf16* __restrict__ Ab, const bf16* __restrict__ Bt,
    const float* __restrict__ bias,
    float* __restrict__ Cout, bf16* __restrict__ Cb, float* __restrict__ rowsq) {
  __shared__ bf16 As[128 * 64];
  __shared__ bf16 Bs[128 * 64];
  int tid = threadIdx.x;
  int bid = blockIdx.x;
  int wid2 = (bid & 7) * 188 + (bid >> 3);  // XCD x owns wid2 in [188x, 188(x+1))
  int mt = wid2 >> 4, nt = wid2 & 15;
  int m0 = mt * 128, n0 = nt * 128;
  int wid = tid >> 6, lane = tid & 63;
  int wm = (wid >> 1) * 64, wn = (wid & 1) * 64;
  int lrow = lane & 15, lko = (lane >> 4) * 8;
  int lr7 = lrow & 7;
  floatx4 acc[4][4] = {};
  int crow = tid >> 3;
  int jg = ((tid & 7) ^ (crow & 7)) * 8;
  const bf16* gA = Ab + (size_t)(m0 + crow) * DD + jg;
  const bf16* gB = Bt + (size_t)(n0 + crow) * DD + jg;
  bf16* lA = As + tid * 8;
  bf16* lB = Bs + tid * 8;
  for (int k0 = 0; k0 < DD; k0 += 64) {
#pragma unroll
    for (int s = 0; s < 4; s++)
      async_lds16(gA + (size_t)(32 * s) * DD + k0, lA + 2048 * s);
#pragma unroll
    for (int s = 0; s < 4; s++)
      async_lds16(gB + (size_t)(32 * s) * DD + k0, lB + 2048 * s);
    __syncthreads();
#pragma unroll
    for (int ks = 0; ks < 64; ks += 32) {
      bf16x8 af[4], bfr[4];
#pragma unroll
      for (int i = 0; i < 4; i++) {
        int sw = (((ks + lko) >> 3) ^ lr7) * 8;
        af[i] = *(const bf16x8*)(As + (wm + i * 16 + lrow) * 64 + sw);
      }
#pragma unroll
      for (int jj = 0; jj < 4; jj++) {
        int sw = (((ks + lko) >> 3) ^ lr7) * 8;
        bfr[jj] = *(const bf16x8*)(Bs + (wn + jj * 16 + lrow) * 64 + sw);
      }
#pragma unroll
      for (int i = 0; i < 4; i++)
#pragma unroll
        for (int jj = 0; jj < 4; jj++)
          acc[i][jj] = __builtin_amdgcn_mfma_f32_16x16x32_bf16(af[i], bfr[jj], acc[i][jj], 0, 0, 0);
    }
    __syncthreads();
  }
  int quad = lane >> 4;
  float bv[4];
#pragma unroll
  for (int jj = 0; jj < 4; jj++) bv[jj] = bias[n0 + wn + jj * 16 + lrow];
#pragma unroll
  for (int i = 0; i < 4; i++) {
#pragma unroll
    for (int r = 0; r < 4; r++) {
      int row = m0 + wm + i * 16 + quad * 4 + r;
      bool ok = (row < NT);
      float sq = 0.f;
#pragma unroll
      for (int jj = 0; jj < 4; jj++) {
        int col = n0 + wn + jj * 16 + lrow;
        float v = acc[i][jj][r] + bv[jj];
        v = fmaxf(v, 0.f);
        if (ok) {
          Cout[(size_t)row * DD + col] = v;
          Cb[(size_t)row * DD + col] = (bf16)v;
        }
        sq += v * v;
      }
#pragma unroll
      for (int m = 1; m < 16; m <<= 1) sq += __shfl_xor(sq, m, 64);
      if (ok && lrow == 0) atomicAdd(&rowsq[row], sq);
    }
  }
}

// ============ EM score pass: 512 thr, 8 waves, in-block split-K =================
// Wave pairs (w, w+4) share staged tiles; w does ks 0..127, w+4 does ks 128..255
// of each 256-wide K-tile. 2x waves/SIMD vs the 4-wave version, half the per-wave
// serial ds_read->MFMA chain. Partial accs combined through LDS at the end.
__global__ __launch_bounds__(512) void k_score(
    const bf16* __restrict__ Xb, const bf16* __restrict__ nmub,
    const float* __restrict__ rowsq,
    float* __restrict__ z, float* __restrict__ rowsum) {
  __shared__ bf16 As[2][64 * 256];   // 64 KB
  __shared__ bf16 Bs[2][16 * 256];   // 16 KB
  __shared__ floatx4 cmb[256];       // 4 KB
  int tid = threadIdx.x, lane = tid & 63, w = tid >> 6;
  int m0 = blockIdx.x * 64, n = blockIdx.y;
  int lrow = lane & 15, lko = (lane >> 4) * 8, lr7 = lrow & 7;
  int scg = tid & 31;
  int srow = tid >> 5;  // [0,16)
  int kg = tid >> 8;    // wave group: 0 (waves 0-3) or 1 (waves 4-7)
  const bf16* gXn = Xb + (size_t)(n * TT + m0) * DD;
  const bf16* gBn = nmub + (size_t)(n * 16) * DD;
#pragma unroll
  for (int r = 0; r < 4; r++) {
    int row = r * 16 + srow;
    int cgg = (scg & 24) | ((scg & 7) ^ (row & 7));
    async_lds16(gXn + (size_t)row * DD + cgg * 8, &As[0][r * 4096 + tid * 8]);
  }
  {
    int row = srow;
    int cgg = (scg & 24) | ((scg & 7) ^ (row & 7));
    if (tid < 512) async_lds16(gBn + (size_t)row * DD + cgg * 8, &Bs[0][tid * 8]);
  }
  floatx4 acc = {};
  int buf = 0;
  int arow = (w & 3) * 16 + lrow;
  for (int k0 = 0; k0 < DD; k0 += 256) {
    __syncthreads();
    if (k0 + 256 < DD) {
#pragma unroll
      for (int r = 0; r < 4; r++) {
        int row = r * 16 + srow;
        int cgg = (scg & 24) | ((scg & 7) ^ (row & 7));
        async_lds16(gXn + (size_t)row * DD + k0 + 256 + cgg * 8,
                    &As[buf ^ 1][r * 4096 + tid * 8]);
      }
      {
        int row = srow;
        int cgg = (scg & 24) | ((scg & 7) ^ (row & 7));
        async_lds16(gBn + (size_t)row * DD + k0 + 256 + cgg * 8, &Bs[buf ^ 1][tid * 8]);
      }
    }
#pragma unroll
    for (int ks = 0; ks < 128; ks += 32) {
      int kss = kg * 128 + ks;
      int cg = (kss + lko) >> 3;
      int cgl = (cg & 24) | ((cg & 7) ^ lr7);
      bf16x8 a = *(const bf16x8*)(&As[buf][arow * 256 + cgl * 8]);
      bf16x8 b = *(const bf16x8*)(&Bs[buf][lrow * 256 + cgl * 8]);
      acc = __builtin_amdgcn_mfma_f32_16x16x32_bf16(a, b, acc, 0, 0, 0);
    }
    buf ^= 1;
  }
  // combine wave-pair partials: waves 4-7 -> LDS, waves 0-3 add
  if (tid >= 256) cmb[tid - 256] = acc;
  __syncthreads();
  if (tid < 256) {
    floatx4 o = cmb[tid];
    acc[0] += o[0]; acc[1] += o[1]; acc[2] += o[2]; acc[3] += o[3];
    int quad = lane >> 4;
    int k = lrow;
    float pacc = 0.f;
#pragma unroll
    for (int r = 0; r < 4; r++) {
      int trow = m0 + w * 16 + quad * 4 + r;
      bool valid = (trow < TT);
      float rq = valid ? rowsq[n * TT + trow] : 1.f;
      float s = acc[r] * (5.f / (sqrtf(rq) + 1e-9f));
      float mx = s;
      mx = fmaxf(mx, __shfl_xor(mx, 1, 64));
      mx = fmaxf(mx, __shfl_xor(mx, 2, 64));
      mx = fmaxf(mx, __shfl_xor(mx, 4, 64));
      float e = __expf(s - mx);
      float se = e;
      se += __shfl_xor(se, 1, 64);
      se += __shfl_xor(se, 2, 64);
      se += __shfl_xor(se, 4, 64);
      float zz = e / se;
      zz = (valid && k < 8) ? zz : 0.f;
      if (valid && k < 8) z[(size_t)(n * TT + trow) * 8 + k] = zz;
      pacc += zz;
    }
    pacc += __shfl_xor(pacc, 16, 64);
    pacc += __shfl_xor(pacc, 32, 64);
    if (lane < 8) atomicAdd(&rowsum[n * 8 + lane], pacc);
  }
}

// ============ EM accumulate: mu_part = z @ X (32 chunks, 2 blocks/CU) ===========
__global__ __launch_bounds__(256) void k_mu_accum(
    const bf16* __restrict__ Xb, const float* __restrict__ z,
    float* __restrict__ part2) {
  int n = blockIdx.x, tc = blockIdx.y, tid = threadIdx.x;
  int t0 = tc * MU_TCH;
  int tcnt = min(MU_TCH, TT - t0);
  __shared__ float zs[MU_TCH * 8];
  for (int i = tid; i < tcnt * 8; i += 256) zs[i] = z[(size_t)(n * TT + t0) * 8 + i];
  __syncthreads();
  float acc[8][8] = {};
  const bf16* xp = Xb + (size_t)(n * TT + t0) * DD + tid * 8;
  bf16x8 x0 = *(const bf16x8*)xp;
  bf16x8 x1 = (tcnt > 1) ? *(const bf16x8*)(xp + DD) : x0;
  for (int tt = 0; tt < tcnt; tt++) {
    bf16x8 cur = x0;
    x0 = x1;
    if (tt + 2 < tcnt) x1 = *(const bf16x8*)(xp + (size_t)(tt + 2) * DD);
    float xv[8];
#pragma unroll
    for (int j = 0; j < 8; j++) xv[j] = (float)cur[j];
    floatx4 za = *(const floatx4*)&zs[tt * 8];
    floatx4 zb4 = *(const floatx4*)&zs[tt * 8 + 4];
    float zk[8] = {za.x, za.y, za.z, za.w, zb4.x, zb4.y, zb4.z, zb4.w};
#pragma unroll
    for (int k = 0; k < 8; k++)
#pragma unroll
      for (int j = 0; j < 8; j++) acc[k][j] += zk[k] * xv[j];
  }
  float* pb = part2 + ((size_t)(tc * 16 + n) * 8) * DD + tid * 8;
#pragma unroll
  for (int k = 0; k < 8; k++) {
    floatx4 lo = {acc[k][0], acc[k][1], acc[k][2], acc[k][3]};
    floatx4 hi = {acc[k][4], acc[k][5], acc[k][6], acc[k][7]};
    *(floatx4*)(pb + (size_t)k * DD) = lo;
    *(floatx4*)(pb + (size_t)k * DD + 4) = hi;
  }
}

// ============ EM finish =========================================================
__global__ void k_mu_finish(const float* __restrict__ part2, const float* __restrict__ rs,
                            float* __restrict__ accS_raw, float* __restrict__ mu_ws,
                            float* __restrict__ mu_out, float* __restrict__ nmu_out,
                            bf16* __restrict__ nmub) {
  int b = blockIdx.x;  // n*8+k
  int n = b >> 3, k = b & 7;
  int tid = threadIdx.x, lane = tid & 63, wid = tid >> 6;
  int d0 = tid * 8;
  float s[8] = {};
#pragma unroll 8
  for (int c = 0; c < MU_CH; c++) {
    const float* p = part2 + ((size_t)(c * 16 + n) * 8 + k) * DD + d0;
    floatx4 a = *(const floatx4*)p;
    floatx4 cc = *(const floatx4*)(p + 4);
    s[0] += a.x; s[1] += a.y; s[2] += a.z; s[3] += a.w;
    s[4] += cc.x; s[5] += cc.y; s[6] += cc.z; s[7] += cc.w;
  }
  if (accS_raw != nullptr) {
#pragma unroll
    for (int j = 0; j < 8; j++) accS_raw[(size_t)b * DD + d0 + j] = s[j];
    return;
  }
  float invr = 1.f / (rs[b] + 1e-9f);
  float m[8];
#pragma unroll
  for (int j = 0; j < 8; j++) m[j] = s[j] * invr;
#pragma unroll
  for (int j = 0; j < 8; j++) mu_ws[(size_t)b * DD + d0 + j] = m[j];
  if (mu_out != nullptr) {
#pragma unroll
    for (int j = 0; j < 8; j++) mu_out[(size_t)b * DD + d0 + j] = m[j];
  }
  float ss = 0.f;
#pragma unroll
  for (int j = 0; j < 8; j++) ss += m[j] * m[j];
  ss = wave_allreduce_sum(ss);
  __shared__ float sb[4];
  if (lane == 0) sb[wid] = ss;
  __syncthreads();
  float inv = 1.f / (sqrtf(sb[0] + sb[1] + sb[2] + sb[3]) + 1e-9f);
  bf16* qb = nmub + (size_t)(n * 16 + k) * DD + d0;
#pragma unroll
  for (int j = 0; j < 8; j++) {
    float nv = m[j] * inv;
    nmu_out[(size_t)b * DD + d0 + j] = nv;
    qb[j] = (bf16)nv;
  }
}

// ============ Woodbury + mu_pred ================================================
__global__ void k_wood_mupred(const float* __restrict__ z, const float* __restrict__ rowsum,
                              const float* __restrict__ S, const float* __restrict__ mu,
                              float* __restrict__ G,
                              const float* __restrict__ nmu, const float* __restrict__ nacf,
                              float* __restrict__ mupred) {
  int tid = threadIdx.x;
  if (blockIdx.x >= 16) {
    int b = blockIdx.x - 16;
    int lane = tid & 63, wid = tid >> 6;
    const float* v = nmu + (size_t)b * DD;
    __shared__ float scr[21];
    for (int c = wid; c < 21; c += 4) {
      const float* a = nacf + (size_t)c * DD;
      float s = 0.f;
      for (int i = lane * 4; i < DD; i += 256) {
        floatx4 vv = *(const floatx4*)(v + i);
        floatx4 aa = *(const floatx4*)(a + i);
        s += vv.x * aa.x + vv.y * aa.y + vv.z * aa.z + vv.w * aa.w;
      }
      s = wave_allreduce_sum(s);
      if (lane == 0) scr[c] = s * 20.f;
    }
    __syncthreads();
    if (tid == 0) {
      float mx = scr[0];
      for (int c = 1; c < 21; c++) mx = fmaxf(mx, scr[c]);
      float se = 0.f;
      for (int c = 0; c < 21; c++) se += __expf(scr[c] - mx);
      float inv = 1.f / se;
      for (int c = 0; c < 21; c++) mupred[(size_t)b * 21 + c] = __expf(scr[c] - mx) * inv;
    }
    return;
  }
  int n = blockIdx.x;
  __shared__ float VU[8][8];
  __shared__ float Mi[8][8];
  __shared__ float invrs[8];
  __shared__ float vus[64][4];
  if (tid < 8) invrs[tid] = 1.f / (rowsum[n * 8 + tid] + 1e-9f);
  {
    int pr = tid >> 2, sl = tid & 3;
    int jj = pr >> 3, kk = pr & 7;
    float s = 0.f;
    for (int t = sl; t < TT; t += 4) {
      const float* zp = z + (size_t)(n * TT + t) * 8;
      s += zp[jj] * zp[kk];
    }
    vus[pr][sl] = s;
  }
  __syncthreads();
  if (tid < 64)
    VU[tid >> 3][tid & 7] =
        (vus[tid][0] + vus[tid][1] + vus[tid][2] + vus[tid][3]) * invrs[tid >> 3];
  __syncthreads();
  if (tid == 0) {
    float M[8][16];
    for (int i = 0; i < 8; i++)
      for (int jj = 0; jj < 8; jj++) {
        M[i][jj] = ((i == jj) ? 1.f : 0.f) - 0.25f * VU[i][jj];
        M[i][8 + jj] = (i == jj) ? 1.f : 0.f;
      }
    for (int c = 0; c < 8; c++) {
      float pv = 1.f / M[c][c];
      for (int jj = 0; jj < 16; jj++) M[c][jj] *= pv;
      for (int rr = 0; rr < 8; rr++)
        if (rr != c) {
          float f = M[rr][c];
          for (int jj = 0; jj < 16; jj++) M[rr][jj] -= f * M[c][jj];
        }
    }
    for (int i = 0; i < 8; i++)
      for (int jj = 0; jj < 8; jj++) Mi[i][jj] = M[i][8 + jj];
  }
  __syncthreads();
  const float* mun = mu + (size_t)n * 8 * DD;
  const float* Sn = S + (size_t)n * 8 * DD;
  float* Gn = G + (size_t)n * 8 * DD;
  for (int d = tid; d < DD; d += 256) {
    float m[8], P[8];
#pragma unroll
    for (int k = 0; k < 8; k++) m[k] = mun[k * DD + d];
#pragma unroll
    for (int k = 0; k < 8; k++) {
      float s = 0.f;
#pragma unroll
      for (int jj = 0; jj < 8; jj++) s += VU[k][jj] * m[jj];
      P[k] = 0.5f * s + Sn[k * DD + d] * invrs[k];
    }
#pragma unroll
    for (int jj = 0; jj < 8; jj++) {
      float s = 0.f;
#pragma unroll
      for (int k = 0; k < 8; k++) s += Mi[jj][k] * P[k];
      Gn[jj * DD + d] = 0.5f * (0.5f * m[jj] + 0.25f * s);
    }
  }
}

// ============ RW pass ===========================================================
__global__ __launch_bounds__(256) void k_rw_passC(
    const bf16* __restrict__ Xb, const float* __restrict__ z,
    const float* __restrict__ G, bf16* __restrict__ refb,
    float* __restrict__ invr) {
  int n = blockIdx.x, ch = blockIdx.y, tid = threadIdx.x;
  int lane = tid & 63, wid = tid >> 6;
  int d0 = tid * 8;
  int t0 = ch * 30;
  const float* Gn = G + (size_t)n * 8 * DD;
  float gr[8][8];
#pragma unroll
  for (int k = 0; k < 8; k++) {
    floatx4 a = *(const floatx4*)(Gn + k * DD + d0);
    floatx4 b = *(const floatx4*)(Gn + k * DD + d0 + 4);
    gr[k][0]=a.x; gr[k][1]=a.y; gr[k][2]=a.z; gr[k][3]=a.w;
    gr[k][4]=b.x; gr[k][5]=b.y; gr[k][6]=b.z; gr[k][7]=b.w;
  }
  __shared__ float red[30][4];
  const bf16* xrow = Xb + (size_t)n * TT * DD;
  bf16x8 xg = *(const bf16x8*)(xrow + (size_t)t0 * DD + d0);
  for (int tt = 0; tt < 30; tt++) {
    int t = t0 + tt;
    bf16x8 x8 = xg;
    if (tt + 1 < 30) xg = *(const bf16x8*)(xrow + (size_t)(t + 1) * DD + d0);
    const float* zp = z + (size_t)(n * TT + t) * 8;
    floatx4 za = *(const floatx4*)zp;
    floatx4 zb4 = *(const floatx4*)(zp + 4);
    float zt[8] = {za.x, za.y, za.z, za.w, zb4.x, zb4.y, zb4.z, zb4.w};
    float r[8];
#pragma unroll
    for (int j = 0; j < 8; j++) {
      float s = 0.5f * (float)x8[j];
#pragma unroll
      for (int k = 0; k < 8; k++) s += zt[k] * gr[k][j];
      r[j] = s;
    }
    bf16x8 ro;
#pragma unroll
    for (int j = 0; j < 8; j++) ro[j] = (bf16)r[j];
    *(bf16x8*)(refb + (size_t)(n * TT + t) * DD + d0) = ro;
    float ss = 0.f;
#pragma unroll
    for (int j = 0; j < 8; j++) ss += r[j] * r[j];
    ss = wave_allreduce_sum(ss);
    if (lane == 0) red[tt][wid] = ss;
  }
  __syncthreads();
  if (tid < 30) {
    float tot = red[tid][0] + red[tid][1] + red[tid][2] + red[tid][3];
    invr[n * TT + t0 + tid] = 1.f / (sqrtf(tot) + 1e-9f);
  }
}

// ============ pred pass1 (BK=256 deep-pipelined staging) ========================
__global__ __launch_bounds__(256) void k_pred_p1(
    const bf16* __restrict__ Xb, const bf16* __restrict__ nacb,
    const float* __restrict__ invn, int mode,
    float* __restrict__ out_frm, float* __restrict__ out_att,
    float* __restrict__ natt, float* __restrict__ att_sums) {
  __shared__ bf16 As[2][32 * 256];
  __shared__ bf16 Bs[2][32 * 256];
  __shared__ float ssum[2][32];
  int tid = threadIdx.x, lane = tid & 63, wid = tid >> 6;
  int m0 = blockIdx.x * 32;
  if (tid < 64) ssum[tid >> 5][tid & 31] = 0.f;
  int lrow = lane & 15, lko = (lane >> 4) * 8, lr7 = lrow & 7;
  int r0 = (wid & 1) * 16, c0 = (wid >> 1) * 16;
  int scg = tid & 31;
  int srow = tid >> 5;
  const bf16* gA = Xb + (size_t)m0 * DD;
  const bf16* gB = nacb;
#pragma unroll
  for (int r = 0; r < 4; r++) {
    int row = r * 8 + srow;
    int cgg = (scg & 24) | ((scg & 7) ^ (row & 7));
    async_lds16(gA + (size_t)row * DD + cgg * 8, &As[0][r * 2048 + tid * 8]);
    async_lds16(gB + (size_t)row * DD + cgg * 8, &Bs[0][r * 2048 + tid * 8]);
  }
  floatx4 acc = {};
  int buf = 0;
  for (int k0 = 0; k0 < DD; k0 += 256) {
    __syncthreads();
    if (k0 + 256 < DD) {
#pragma unroll
      for (int r = 0; r < 4; r++) {
        int row = r * 8 + srow;
        int cgg = (scg & 24) | ((scg & 7) ^ (row & 7));
        async_lds16(gA + (size_t)row * DD + k0 + 256 + cgg * 8,
                    &As[buf ^ 1][r * 2048 + tid * 8]);
        async_lds16(gB + (size_t)row * DD + k0 + 256 + cgg * 8,
                    &Bs[buf ^ 1][r * 2048 + tid * 8]);
      }
    }
#pragma unroll
    for (int ks = 0; ks < 256; ks += 32) {
      int cg = (ks + lko) >> 3;
      int cgl = (cg & 24) | ((cg & 7) ^ lr7);
      bf16x8 a = *(const bf16x8*)(&As[buf][(r0 + lrow) * 256 + cgl * 8]);
      bf16x8 b = *(const bf16x8*)(&Bs[buf][(c0 + lrow) * 256 + cgl * 8]);
      acc = __builtin_amdgcn_mfma_f32_16x16x32_bf16(a, b, acc, 0, 0, 0);
    }
    buf ^= 1;
  }
  __syncthreads();
  int quad = lane >> 4;
  int nbase = m0 / TT;
  int c = c0 + lrow;
#pragma unroll
  for (int r = 0; r < 4; r++) {
    int row = m0 + r0 + quad * 4 + r;
    if (c < 22) {
      float iv = mode ? (1.f / (sqrtf(invn[row]) + 1e-9f)) : invn[row];
      float s = acc[r] * iv * 20.f;
      float sg = 1.f / (1.f + __expf(-s));
      int n_loc = row / TT - nbase;
      if (c < 21) out_frm[(size_t)row * 21 + c] = s;
      else out_att[row] = sg;
      natt[(size_t)row * 22 + c] = sg;
      atomicAdd(&ssum[n_loc][c], sg);
    }
  }
  __syncthreads();
  if (tid < 64) {
    int nl = tid >> 5, cs = tid & 31;
    int nn = nbase + nl;
    if (cs < 22 && nn < NB) {
      float v = ssum[nl][cs];
      if (v != 0.f) atomicAdd(&att_sums[nn * 22 + cs], v);
    }
  }
}

// ============ pred pass2 (16 t-chunks of 47, 2 blocks/CU) =======================
__global__ __launch_bounds__(256) void k_pred_p2(
    const bf16* __restrict__ Xb, const float* __restrict__ natt,
    const float* __restrict__ sums, float* __restrict__ partF) {
  int n = blockIdx.x, dh = blockIdx.y, tc = blockIdx.z, tid = threadIdx.x;
  int d = dh * 1024 + tid * 4;
  int t0 = tc * PF_TCH;
  int tcnt = min(PF_TCH, TT - t0);
  __shared__ float sw[PF_TCH * 22];
  for (int i = tid; i < tcnt * 22; i += 256) {
    int c = i - (i / 22) * 22;
    sw[i] = natt[(size_t)(n * TT + t0) * 22 + i] / (sums[n * 22 + c] + 1e-5f);
  }
  __syncthreads();
  float ac[22][4] = {};
  const bf16* xrow = Xb + (size_t)n * TT * DD;
  bf16x4 xg = *(const bf16x4*)(xrow + (size_t)t0 * DD + d);
  for (int tt = 0; tt < tcnt; tt++) {
    bf16x4 x4 = xg;
    if (tt + 1 < tcnt) xg = *(const bf16x4*)(xrow + (size_t)(t0 + tt + 1) * DD + d);
    float xv[4] = {(float)x4[0], (float)x4[1], (float)x4[2], (float)x4[3]};
#pragma unroll
    for (int cidx = 0; cidx < 22; cidx++) {
      float w = sw[tt * 22 + cidx];
#pragma unroll
      for (int jj = 0; jj < 4; jj++) ac[cidx][jj] += w * xv[jj];
    }
  }
  float* pb = partF + ((size_t)(n * PF_CH + tc) * 22) * DD + d;
#pragma unroll
  for (int cidx = 0; cidx < 22; cidx++) {
    floatx4 v = {ac[cidx][0], ac[cidx][1], ac[cidx][2], ac[cidx][3]};
    *(floatx4*)(pb + (size_t)cidx * DD) = v;
  }
}

// ============ reduce feats partials (full-BW grid) ==============================
__global__ void k_feat_finish(const float* __restrict__ partF, float* __restrict__ feats) {
  int idx = blockIdx.x * 256 + threadIdx.x;
  if (idx >= NB * 22 * DD) return;
  int n = idx / (22 * DD);
  int rem = idx - n * (22 * DD);
  const float* p = partF + ((size_t)n * PF_CH) * (22 * DD) + rem;
  float s = 0.f;
#pragma unroll
  for (int tc = 0; tc < PF_CH; tc++) s += p[(size_t)tc * 22 * DD];
  feats[idx] = s;
}

// ============ final scores + softmax ============================================
__global__ void k_pred_final(const float* __restrict__ feats, const float* __restrict__ nacf,
                             float* __restrict__ oca, float* __restrict__ ocw) {
  int n = blockIdx.x, tid = threadIdx.x, lane = tid & 63, wid = tid >> 6;
  const float* fn = feats + (size_t)n * 22 * DD;
  __shared__ float rnorm[22];
  __shared__ float scr[42];
  for (int r = wid; r < 22; r += 4) {
    const float* fv = fn + (size_t)r * DD;
    float s = 0.f;
    for (int i = lane * 4; i < DD; i += 256) {
      floatx4 v = *(const floatx4*)(fv + i);
      s += v.x * v.x + v.y * v.y + v.z * v.z + v.w * v.w;
    }
    s = wave_allreduce_sum(s);
    if (lane == 0) rnorm[r] = 1.f / (sqrtf(s) + 1e-9f);
  }
  __syncthreads();
  for (int idx = wid; idx < 42; idx += 4) {
    int c = (idx < 21) ? idx : (idx - 21);
    int fr = (idx < 21) ? c : 21;
    const float* fv = fn + (size_t)fr * DD;
    const float* av = nacf + (size_t)c * DD;
    float s = 0.f;
    for (int i = lane * 4; i < DD; i += 256) {
      floatx4 v = *(const floatx4*)(fv + i);
      floatx4 a = *(const floatx4*)(av + i);
      s += v.x * a.x + v.y * a.y + v.z * a.z + v.w * a.w;
    }
    s = wave_allreduce_sum(s);
    if (lane == 0) scr[idx] = s * 20.f * rnorm[fr];
  }
  __syncthreads();
  if (tid < 2) {
    int base = (tid == 0) ? 21 : 0;
    float* dst = ((tid == 0) ? oca : ocw) + (size_t)n * 21;
    float mx = scr[base];
    for (int c = 1; c < 21; c++) mx = fmaxf(mx, scr[base + c]);
    float se = 0.f;
    for (int c = 0; c < 21; c++) se += __expf(scr[base + c] - mx);
    float inv = 1.f / se;
    for (int c = 0; c < 21; c++) dst[c] = __expf(scr[base + c] - mx) * inv;
  }
}

extern "C" void kernel_launch(void* const* d_in, const int* in_sizes, int n_in,
                              void* d_out, int out_size, void* d_ws, size_t ws_size,
                              hipStream_t stream) {
  const float* x_in = (const float*)d_in[0];
  const float* W = (const float*)d_in[1];
  const float* bemb = (const float*)d_in[2];
  const float* mup = (const float*)d_in[3];
  const float* ac = (const float*)d_in[4];
  const float* fg = (const float*)d_in[5];
  float* out = (float*)d_out;

  char* ws = (char*)d_ws;
  bf16* Wt = (bf16*)ws;                       // 8,388,608
  bf16* Xb = (bf16*)(ws + 8388608);           // 49,283,072 (12032 rows)
  bf16* Rb = (bf16*)(ws + 57671680);          // 49,283,072
  bf16* Ab = (bf16*)(ws + 106954752);         // 49,283,072 (alias: part2 / partF)
  float* part2 = (float*)(ws + 106954752);    // 33.5 MB (EM phase, 32 chunks)
  float* partF = (float*)(ws + 106954752);    // 46.1 MB (pred phase, 16 chunks)
  bf16* nacb = (bf16*)(ws + 156237824);       // 131,072
  float* f = (float*)(ws + 156368896);
  float* nacf = f;                       // 45,056
  float* mu = nacf + 45056;              // 262,144
  float* nmu = mu + 262144;              // 262,144
  bf16* nmub = (bf16*)(nmu + 262144);    // 262,144 floats worth (1 MB)
  float* accS = nmu + 262144 + 262144;   // 262,144
  float* G = accS + 262144;              // 262,144
  float* z = G + 262144;                 // 96,000  [n][750][8]
  float* natt = z + 96000;               // 264,000
  float* feats = natt + 264000;          // 720,896
  float* invr = feats + 720896;          // 12,032
  float* rowsum = invr + 12032;          // 768 (zeroed)
  float* asums_o = rowsum + 768;         // 352 (zeroed)
  float* asums_m = asums_o + 352;        // 352 (zeroed)
  float* rowsq = asums_m + 352;          // 12,032 (zeroed)

  float* o_ca = out;
  float* o_cw = out + 336;
  float* o_att = out + 672;
  float* o_frm = out + 12672;
  float* m_ca = out + 264672;
  float* m_cw = out + 265008;
  float* m_att = out + 265344;
  float* m_frm = out + 277344;
  float* x_out = out + 529344;
  float* mu_out = out + 25105344;
  float* mup_out = out + 25367488;

  hipMemsetAsync(rowsum, 0, (768 + 352 + 352 + 12032) * sizeof(float), stream);
  hipMemsetAsync(nmub, 0, (size_t)NB * 16 * DD * sizeof(bf16), stream);
  k_prep<<<7264, 256, 0, stream>>>(W, Wt, ac, fg, nacf, nacb, mup, nmu, nmub, x_in, Ab);
  k_gemm<<<1504, 256, 0, stream>>>(Ab, Wt, bemb, x_out, Xb, rowsq);
  for (int it = 0; it < 5; it++) {
    bool last = (it == 4);
    k_score<<<dim3(12, 16), 512, 0, stream>>>(Xb, nmub, rowsq, z, rowsum + it * 128);
    k_mu_accum<<<dim3(16, MU_CH), 256, 0, stream>>>(Xb, z, part2);
    k_mu_finish<<<128, 256, 0, stream>>>(part2, rowsum + it * 128, nullptr, mu,
                                         last ? mu_out : nullptr, nmu, nmub);
  }
  k_score<<<dim3(12, 16), 512, 0, stream>>>(Xb, nmub, rowsq, z, rowsum + 5 * 128);
  k_mu_accum<<<dim3(16, MU_CH), 256, 0, stream>>>(Xb, z, part2);
  k_mu_finish<<<128, 256, 0, stream>>>(part2, nullptr, accS, nullptr, nullptr, nullptr, nullptr);
  k_wood_mupred<<<144, 256, 0, stream>>>(z, rowsum + 5 * 128, accS, mu, G, nmu, nacf, mup_out);
  k_rw_passC<<<dim3(16, 25), 256, 0, stream>>>(Xb, z, G, Rb, invr);
  // o-phase (on x)
  k_pred_p1<<<375, 256, 0, stream>>>(Xb, nacb, rowsq, 1, o_frm, o_att, natt, asums_o);
  k_pred_p2<<<dim3(16, 2, PF_CH), 256, 0, stream>>>(Xb, natt, asums_o, partF);
  k_feat_finish<<<2816, 256, 0, stream>>>(partF, feats);
  k_pred_final<<<16, 256, 0, stream>>>(feats, nacf, o_ca, o_cw);
  // m-phase (on refined)
  k_pred_p1<<<375, 256, 0, stream>>>(Rb, nacb, invr, 0, m_frm, m_att, natt, asums_m);
  k_pred_p2<<<dim3(16, 2, PF_CH), 256, 0, stream>>>(Rb, natt, asums_m, partF);
  k_feat_finish<<<2816, 256, 0, stream>>>(partF, feats);
  k_pred_final<<<16, 256, 0, stream>>>(feats, nacf, m_ca, m_cw);
}